// Round 1
// baseline (975.489 us; speedup 1.0000x reference)
//
#include <hip/hip_runtime.h>
#include <hip/hip_bf16.h>

// DistGAT: 3-layer GAT, N=50000 nodes, E=800000 edges.
// Strategy: build CSR by dst once, then per layer: f32 tiled GEMM (no fp32 MFMA
// on CDNA4), el/er dots, per-(dst,head) softmax stats over CSR, wave-per-dst
// weighted aggregation with fused bias/residual/ELU (and head-mean for L3).
// Workspace use: ~187.5 MB.

#define NODES 50000
#define EDGES 800000
#define NEG 0.2f

// ---------------------------------------------------------------- CSR build
__global__ void k_hist(const int* __restrict__ dst, int* __restrict__ cnt, int e) {
    int gid = blockIdx.x * blockDim.x + threadIdx.x;
    if (gid < e) atomicAdd(&cnt[dst[gid]], 1);
}

__global__ __launch_bounds__(1024) void k_scan(const int* __restrict__ deg,
                                               int* __restrict__ offs, int n) {
    const int CH = (n + 1023) / 1024;   // 49
    int t = threadIdx.x;
    int base = t * CH;
    int s = 0;
    for (int j = 0; j < CH; ++j) {
        int i = base + j;
        if (i < n) s += deg[i];
    }
    __shared__ int sm[1024];
    sm[t] = s;
    __syncthreads();
    for (int off = 1; off < 1024; off <<= 1) {
        int v = (t >= off) ? sm[t - off] : 0;
        __syncthreads();
        sm[t] += v;
        __syncthreads();
    }
    int run = sm[t] - s;  // exclusive prefix
    for (int j = 0; j < CH; ++j) {
        int i = base + j;
        if (i < n) { offs[i] = run; run += deg[i]; }
    }
    if (t == 1023) offs[n] = sm[1023];
}

__global__ void k_fill(const int* __restrict__ src, const int* __restrict__ dst,
                       const int* __restrict__ offs, int* __restrict__ cur,
                       int* __restrict__ csr, int e) {
    int gid = blockIdx.x * blockDim.x + threadIdx.x;
    if (gid < e) {
        int d = dst[gid];
        int pos = offs[d] + atomicAdd(&cur[d], 1);
        csr[pos] = src[gid];
    }
}

// ---------------------------------------------------------------- GEMM
// C[N,F] = A[N,128] @ B[128,F].  64x64 tile, 256 thr, 4x4 micro, K-tile 64.
template <int F>
__global__ __launch_bounds__(256) void k_gemm(const float* __restrict__ A,
                                              const float* __restrict__ B,
                                              float* __restrict__ C, int nrows) {
    __shared__ float At[64][65];  // At[k_local][row], pad breaks write conflicts
    __shared__ float Bs[64][68];  // Bs[k_local][col], 16B-aligned rows
    const int t  = threadIdx.x;
    const int n0 = blockIdx.x * 64;
    const int r0 = (t & 15) * 4;
    const int c0 = (t >> 4) * 4;

    for (int ct = 0; ct < F / 64; ++ct) {
        float acc[4][4];
#pragma unroll
        for (int i = 0; i < 4; ++i)
#pragma unroll
            for (int j = 0; j < 4; ++j) acc[i][j] = 0.f;

        for (int kt = 0; kt < 2; ++kt) {
            __syncthreads();
            // stage A (transposed) : 64 rows x 64 k
            {
                const int c4 = (t & 15) * 4;
#pragma unroll
                for (int p = 0; p < 4; ++p) {
                    int row = p * 16 + (t >> 4);
                    int gr  = n0 + row;
                    float4 v = make_float4(0.f, 0.f, 0.f, 0.f);
                    if (gr < nrows)
                        v = *reinterpret_cast<const float4*>(A + (size_t)gr * 128 + kt * 64 + c4);
                    At[c4 + 0][row] = v.x;
                    At[c4 + 1][row] = v.y;
                    At[c4 + 2][row] = v.z;
                    At[c4 + 3][row] = v.w;
                }
            }
            // stage B : 64 k x 64 cols
            {
                const int c4 = (t & 15) * 4;
#pragma unroll
                for (int p = 0; p < 4; ++p) {
                    int k = p * 16 + (t >> 4);
                    *reinterpret_cast<float4*>(&Bs[k][c4]) =
                        *reinterpret_cast<const float4*>(B + (size_t)(kt * 64 + k) * F + ct * 64 + c4);
                }
            }
            __syncthreads();
#pragma unroll 4
            for (int k = 0; k < 64; ++k) {
                float4 bv = *reinterpret_cast<const float4*>(&Bs[k][c0]);
                float a0 = At[k][r0 + 0];
                float a1 = At[k][r0 + 1];
                float a2 = At[k][r0 + 2];
                float a3 = At[k][r0 + 3];
                acc[0][0] = fmaf(a0, bv.x, acc[0][0]);
                acc[0][1] = fmaf(a0, bv.y, acc[0][1]);
                acc[0][2] = fmaf(a0, bv.z, acc[0][2]);
                acc[0][3] = fmaf(a0, bv.w, acc[0][3]);
                acc[1][0] = fmaf(a1, bv.x, acc[1][0]);
                acc[1][1] = fmaf(a1, bv.y, acc[1][1]);
                acc[1][2] = fmaf(a1, bv.z, acc[1][2]);
                acc[1][3] = fmaf(a1, bv.w, acc[1][3]);
                acc[2][0] = fmaf(a2, bv.x, acc[2][0]);
                acc[2][1] = fmaf(a2, bv.y, acc[2][1]);
                acc[2][2] = fmaf(a2, bv.z, acc[2][2]);
                acc[2][3] = fmaf(a2, bv.w, acc[2][3]);
                acc[3][0] = fmaf(a3, bv.x, acc[3][0]);
                acc[3][1] = fmaf(a3, bv.y, acc[3][1]);
                acc[3][2] = fmaf(a3, bv.z, acc[3][2]);
                acc[3][3] = fmaf(a3, bv.w, acc[3][3]);
            }
        }
#pragma unroll
        for (int i = 0; i < 4; ++i) {
            int gr = n0 + r0 + i;
            if (gr < nrows)
                *reinterpret_cast<float4*>(C + (size_t)gr * F + ct * 64 + c0) =
                    make_float4(acc[i][0], acc[i][1], acc[i][2], acc[i][3]);
        }
    }
}

// ---------------------------------------------------------------- el / er
template <int H, int D>
__global__ void k_elr(const float* __restrict__ feat, const float* __restrict__ al,
                      const float* __restrict__ ar, float* __restrict__ el,
                      float* __restrict__ er, int total) {
    int gid = blockIdx.x * blockDim.x + threadIdx.x;
    if (gid >= total) return;
    int n = gid / H, h = gid - n * H;
    const float4* f = reinterpret_cast<const float4*>(feat + (size_t)n * (H * D) + h * D);
    const float4* a = reinterpret_cast<const float4*>(al + h * D);
    const float4* r = reinterpret_cast<const float4*>(ar + h * D);
    float sl = 0.f, sr = 0.f;
#pragma unroll
    for (int j = 0; j < D / 4; ++j) {
        float4 fv = f[j], av = a[j], rv = r[j];
        sl += fv.x * av.x + fv.y * av.y + fv.z * av.z + fv.w * av.w;
        sr += fv.x * rv.x + fv.y * rv.y + fv.z * rv.z + fv.w * rv.w;
    }
    el[gid] = sl;
    er[gid] = sr;
}

// ---------------------------------------------------------------- softmax stats
template <int H>
__global__ void k_stats(const float* __restrict__ el, const float* __restrict__ er,
                        const int* __restrict__ csr, const int* __restrict__ offs,
                        float* __restrict__ mb, float* __restrict__ invs, int total) {
    int gid = blockIdx.x * blockDim.x + threadIdx.x;
    if (gid >= total) return;
    int n = gid / H, h = gid - n * H;
    int o0 = offs[n], o1 = offs[n + 1];
    float erv = er[gid];
    float m = -1e30f;
    for (int p = o0; p < o1; ++p) {
        float e = el[csr[p] * H + h] + erv;
        e = (e > 0.f) ? e : NEG * e;
        m = fmaxf(m, e);
    }
    float s = 0.f;
    for (int p = o0; p < o1; ++p) {
        float e = el[csr[p] * H + h] + erv;
        e = (e > 0.f) ? e : NEG * e;
        s += __expf(e - m);
    }
    mb[gid]  = m;
    invs[gid] = (o1 > o0) ? (1.f / s) : 0.f;
}

// ---------------------------------------------------------------- aggregation, F=128 (H=4,D=32)
// one wave per dst node; lane owns features {lane, 64+lane}; fused bias+res+ELU.
// NOTE: res and out may alias (layer-2 in-place residual) -> no __restrict__.
template <bool HASRES>
__global__ __launch_bounds__(256) void k_aggr128(
    const float* __restrict__ feat, const int* __restrict__ csr,
    const int* __restrict__ offs, const float* __restrict__ el,
    const float* __restrict__ er, const float* __restrict__ mb,
    const float* __restrict__ invs, const float* __restrict__ bias,
    const float* res, float* out, int nnodes) {
    int node = blockIdx.x * 4 + (threadIdx.x >> 6);
    if (node >= nnodes) return;
    int lane = threadIdx.x & 63;
    int h0 = lane >> 5;             // b=0 head: h0 ; b=1 head: 2+h0
    int i0 = node * 4 + h0;
    int i1 = node * 4 + 2 + h0;
    float er0 = er[i0], m0 = mb[i0], v0 = invs[i0];
    float er1 = er[i1], m1 = mb[i1], v1 = invs[i1];
    int o0 = offs[node], o1 = offs[node + 1];
    float acc0 = 0.f, acc1 = 0.f;
    for (int p = o0; p < o1; ++p) {
        int s = csr[p];
        const float* fs = feat + (size_t)s * 128;
        float e0 = el[s * 4 + h0] + er0;
        e0 = (e0 > 0.f) ? e0 : NEG * e0;
        float a0 = __expf(e0 - m0) * v0;
        acc0 = fmaf(a0, fs[lane], acc0);
        float e1 = el[s * 4 + 2 + h0] + er1;
        e1 = (e1 > 0.f) ? e1 : NEG * e1;
        float a1 = __expf(e1 - m1) * v1;
        acc1 = fmaf(a1, fs[64 + lane], acc1);
    }
    float r0 = acc0 + bias[lane]      + (HASRES ? res[(size_t)node * 128 + lane]      : 0.f);
    float r1 = acc1 + bias[64 + lane] + (HASRES ? res[(size_t)node * 128 + 64 + lane] : 0.f);
    r0 = (r0 > 0.f) ? r0 : (__expf(r0) - 1.f);   // ELU
    r1 = (r1 > 0.f) ? r1 : (__expf(r1) - 1.f);
    out[(size_t)node * 128 + lane]      = r0;
    out[(size_t)node * 128 + 64 + lane] = r1;
}

// ---------------------------------------------------------------- aggregation, F=384 (H=6,D=64)
// lane owns feature b*64+lane for b=0..5 (head b); fused res3+b3+head-mean.
__global__ __launch_bounds__(256) void k_aggr384(
    const float* __restrict__ feat, const int* __restrict__ csr,
    const int* __restrict__ offs, const float* __restrict__ el,
    const float* __restrict__ er, const float* __restrict__ mb,
    const float* __restrict__ invs, const float* __restrict__ b3,
    const float* __restrict__ res3, float* __restrict__ out, int nnodes) {
    int node = blockIdx.x * 4 + (threadIdx.x >> 6);
    if (node >= nnodes) return;
    int lane = threadIdx.x & 63;
    float erv[6], mv[6], iv[6];
#pragma unroll
    for (int b = 0; b < 6; ++b) {
        int i = node * 6 + b;
        erv[b] = er[i];
        mv[b]  = mb[i];
        iv[b]  = invs[i];
    }
    float acc[6] = {0.f, 0.f, 0.f, 0.f, 0.f, 0.f};
    int o0 = offs[node], o1 = offs[node + 1];
    for (int p = o0; p < o1; ++p) {
        int s = csr[p];
        const float* fs = feat + (size_t)s * 384;
        const float* es = el + (size_t)s * 6;
#pragma unroll
        for (int b = 0; b < 6; ++b) {
            float e = es[b] + erv[b];
            e = (e > 0.f) ? e : NEG * e;
            float a = __expf(e - mv[b]) * iv[b];
            acc[b] = fmaf(a, fs[b * 64 + lane], acc[b]);
        }
    }
    float sum = 0.f;
#pragma unroll
    for (int b = 0; b < 6; ++b)
        sum += acc[b] + res3[(size_t)node * 384 + b * 64 + lane] + b3[b * 64 + lane];
    out[(size_t)node * 64 + lane] = sum * (1.f / 6.f);
}

// ---------------------------------------------------------------- launch
extern "C" void kernel_launch(void* const* d_in, const int* in_sizes, int n_in,
                              void* d_out, int out_size, void* d_ws, size_t ws_size,
                              hipStream_t stream) {
    const float* x     = (const float*)d_in[0];
    const int*   src   = (const int*)d_in[1];
    const int*   dst   = (const int*)d_in[2];
    const float* W1    = (const float*)d_in[3];
    const float* al1   = (const float*)d_in[4];
    const float* ar1   = (const float*)d_in[5];
    const float* b1    = (const float*)d_in[6];
    const float* W2    = (const float*)d_in[7];
    const float* al2   = (const float*)d_in[8];
    const float* ar2   = (const float*)d_in[9];
    const float* b2    = (const float*)d_in[10];
    const float* W3    = (const float*)d_in[11];
    const float* al3   = (const float*)d_in[12];
    const float* ar3   = (const float*)d_in[13];
    const float* b3    = (const float*)d_in[14];
    const float* Wres3 = (const float*)d_in[15];
    float* out = (float*)d_out;

    const int N = NODES, E = EDGES;

    // workspace carve-up (256B aligned); total ~187.5 MB
    char*  ws = (char*)d_ws;
    size_t o  = 0;
    auto alloc = [&](size_t bytes) {
        size_t r = o;
        o += (bytes + 255) & ~(size_t)255;
        return r;
    };
    int*   offs = (int*)(ws + alloc((size_t)(N + 1) * 4));
    int*   cnt  = (int*)(ws + alloc((size_t)N * 4));
    int*   csr  = (int*)(ws + alloc((size_t)E * 4));
    float* el   = (float*)(ws + alloc((size_t)N * 6 * 4));
    float* er   = (float*)(ws + alloc((size_t)N * 6 * 4));
    float* mb   = (float*)(ws + alloc((size_t)N * 6 * 4));
    float* invs = (float*)(ws + alloc((size_t)N * 6 * 4));
    float* bufA = (float*)(ws + alloc((size_t)N * 384 * 4));  // projected feat
    float* bufB = (float*)(ws + alloc((size_t)N * 384 * 4));  // res3
    float* bufC = (float*)(ws + alloc((size_t)N * 128 * 4));  // h1 then h2 (in place)

    const int gE  = (E + 255) / 256;
    const int g4  = (N * 4 + 255) / 256;
    const int g6  = (N * 6 + 255) / 256;
    const int gA  = (N + 3) / 4;
    const int gG  = (N + 63) / 64;

    // ---- CSR by dst
    hipMemsetAsync(cnt, 0, (size_t)N * 4, stream);
    k_hist<<<gE, 256, 0, stream>>>(dst, cnt, E);
    k_scan<<<1, 1024, 0, stream>>>(cnt, offs, N);
    hipMemsetAsync(cnt, 0, (size_t)N * 4, stream);
    k_fill<<<gE, 256, 0, stream>>>(src, dst, offs, cnt, csr, E);

    // ---- layer 1: x -> h1 (bufC)
    k_gemm<128><<<gG, 256, 0, stream>>>(x, W1, bufA, N);
    k_elr<4, 32><<<g4, 256, 0, stream>>>(bufA, al1, ar1, el, er, N * 4);
    k_stats<4><<<g4, 256, 0, stream>>>(el, er, csr, offs, mb, invs, N * 4);
    k_aggr128<false><<<gA, 256, 0, stream>>>(bufA, csr, offs, el, er, mb, invs,
                                             b1, nullptr, bufC, N);

    // ---- layer 2: h1 -> h2 (bufC in place; residual = h1)
    k_gemm<128><<<gG, 256, 0, stream>>>(bufC, W2, bufA, N);
    k_elr<4, 32><<<g4, 256, 0, stream>>>(bufA, al2, ar2, el, er, N * 4);
    k_stats<4><<<g4, 256, 0, stream>>>(el, er, csr, offs, mb, invs, N * 4);
    k_aggr128<true><<<gA, 256, 0, stream>>>(bufA, csr, offs, el, er, mb, invs,
                                            b2, bufC, bufC, N);

    // ---- layer 3: h2 -> out (residual = h2 @ Wres3, fused head-mean)
    k_gemm<384><<<gG, 256, 0, stream>>>(bufC, W3, bufA, N);
    k_gemm<384><<<gG, 256, 0, stream>>>(bufC, Wres3, bufB, N);
    k_elr<6, 64><<<g6, 256, 0, stream>>>(bufA, al3, ar3, el, er, N * 6);
    k_stats<6><<<g6, 256, 0, stream>>>(el, er, csr, offs, mb, invs, N * 6);
    k_aggr384<<<gA, 256, 0, stream>>>(bufA, csr, offs, el, er, mb, invs,
                                      b3, bufB, out, N);
}

// Round 2
// 785.227 us; speedup vs baseline: 1.2423x; 1.2423x over previous
//
#include <hip/hip_runtime.h>
#include <hip/hip_bf16.h>

// DistGAT: 3-layer GAT, N=50000 nodes, E=800000 edges.
// R2: (1) max-free segment softmax fused into aggregation (k_stats removed),
//     (2) layer-3 gathers in bf16 (feat + res3 quantized in GEMM epilogue),
//     (3) GEMMs stage A once per block; layer-3 W3/Wres3 fused in one kernel,
//     (4) 2-edge unroll in aggregators.
// Workspace ~185 MB (fits the 187.5 MB footprint proven in R1).

#define NODES 50000
#define EDGES 800000
#define NEG 0.2f

__device__ __forceinline__ float leaky(float e) { return e > 0.f ? e : NEG * e; }
__device__ __forceinline__ float bf2f(unsigned short u) {
    return __uint_as_float(((unsigned)u) << 16);
}
__device__ __forceinline__ unsigned f2bf(float f) {  // RNE, low 16 bits valid
    unsigned u = __float_as_uint(f);
    return (u + 0x7fffu + ((u >> 16) & 1u)) >> 16;
}

// ---------------------------------------------------------------- CSR build
__global__ void k_hist(const int* __restrict__ dst, int* __restrict__ cnt, int e) {
    int gid = blockIdx.x * blockDim.x + threadIdx.x;
    if (gid < e) atomicAdd(&cnt[dst[gid]], 1);
}

__global__ __launch_bounds__(1024) void k_scan(const int* __restrict__ deg,
                                               int* __restrict__ offs, int n) {
    const int CH = (n + 1023) / 1024;
    int t = threadIdx.x;
    int base = t * CH;
    int s = 0;
    for (int j = 0; j < CH; ++j) {
        int i = base + j;
        if (i < n) s += deg[i];
    }
    __shared__ int sm[1024];
    sm[t] = s;
    __syncthreads();
    for (int off = 1; off < 1024; off <<= 1) {
        int v = (t >= off) ? sm[t - off] : 0;
        __syncthreads();
        sm[t] += v;
        __syncthreads();
    }
    int run = sm[t] - s;
    for (int j = 0; j < CH; ++j) {
        int i = base + j;
        if (i < n) { offs[i] = run; run += deg[i]; }
    }
    if (t == 1023) offs[n] = sm[1023];
}

__global__ void k_fill(const int* __restrict__ src, const int* __restrict__ dst,
                       const int* __restrict__ offs, int* __restrict__ cur,
                       int* __restrict__ csr, int e) {
    int gid = blockIdx.x * blockDim.x + threadIdx.x;
    if (gid < e) {
        int d = dst[gid];
        int pos = offs[d] + atomicAdd(&cur[d], 1);
        csr[pos] = src[gid];
    }
}

// ---------------------------------------------------------------- GEMM, F=128
// C[N,128] = A[N,128] @ B[128,128]. A staged ONCE per block (64 rows x 128 K).
__global__ __launch_bounds__(256) void k_gemm128(const float* __restrict__ A,
                                                 const float* __restrict__ B,
                                                 float* __restrict__ C, int nrows) {
    __shared__ float At[128][65];  // [k][row]
    __shared__ float Bs[64][68];   // [k][col]
    const int t  = threadIdx.x;
    const int n0 = blockIdx.x * 64;
    const int r0 = (t & 15) * 4;
    const int c0 = (t >> 4) * 4;
    const int c4 = (t & 15) * 4;
    const int rr = t >> 4;

#pragma unroll
    for (int half = 0; half < 2; ++half)
#pragma unroll
        for (int p = 0; p < 4; ++p) {
            int row = p * 16 + rr;
            int gr  = n0 + row;
            float4 v = make_float4(0.f, 0.f, 0.f, 0.f);
            if (gr < nrows)
                v = *reinterpret_cast<const float4*>(A + (size_t)gr * 128 + half * 64 + c4);
            At[half * 64 + c4 + 0][row] = v.x;
            At[half * 64 + c4 + 1][row] = v.y;
            At[half * 64 + c4 + 2][row] = v.z;
            At[half * 64 + c4 + 3][row] = v.w;
        }

    for (int ct = 0; ct < 2; ++ct) {
        float acc[4][4];
#pragma unroll
        for (int i = 0; i < 4; ++i)
#pragma unroll
            for (int j = 0; j < 4; ++j) acc[i][j] = 0.f;

        for (int kt = 0; kt < 2; ++kt) {
            __syncthreads();
#pragma unroll
            for (int p = 0; p < 4; ++p) {
                int k = p * 16 + rr;
                *reinterpret_cast<float4*>(&Bs[k][c4]) =
                    *reinterpret_cast<const float4*>(B + (size_t)(kt * 64 + k) * 128 + ct * 64 + c4);
            }
            __syncthreads();
#pragma unroll 4
            for (int k = 0; k < 64; ++k) {
                float4 bv = *reinterpret_cast<const float4*>(&Bs[k][c0]);
                float a0 = At[kt * 64 + k][r0 + 0];
                float a1 = At[kt * 64 + k][r0 + 1];
                float a2 = At[kt * 64 + k][r0 + 2];
                float a3 = At[kt * 64 + k][r0 + 3];
                acc[0][0] = fmaf(a0, bv.x, acc[0][0]); acc[0][1] = fmaf(a0, bv.y, acc[0][1]);
                acc[0][2] = fmaf(a0, bv.z, acc[0][2]); acc[0][3] = fmaf(a0, bv.w, acc[0][3]);
                acc[1][0] = fmaf(a1, bv.x, acc[1][0]); acc[1][1] = fmaf(a1, bv.y, acc[1][1]);
                acc[1][2] = fmaf(a1, bv.z, acc[1][2]); acc[1][3] = fmaf(a1, bv.w, acc[1][3]);
                acc[2][0] = fmaf(a2, bv.x, acc[2][0]); acc[2][1] = fmaf(a2, bv.y, acc[2][1]);
                acc[2][2] = fmaf(a2, bv.z, acc[2][2]); acc[2][3] = fmaf(a2, bv.w, acc[2][3]);
                acc[3][0] = fmaf(a3, bv.x, acc[3][0]); acc[3][1] = fmaf(a3, bv.y, acc[3][1]);
                acc[3][2] = fmaf(a3, bv.z, acc[3][2]); acc[3][3] = fmaf(a3, bv.w, acc[3][3]);
            }
        }
#pragma unroll
        for (int i = 0; i < 4; ++i) {
            int gr = n0 + r0 + i;
            if (gr < nrows)
                *reinterpret_cast<float4*>(C + (size_t)gr * 128 + ct * 64 + c0) =
                    make_float4(acc[i][0], acc[i][1], acc[i][2], acc[i][3]);
        }
    }
}

// ---------------------------------------------------------------- GEMM, layer 3 fused
// C1 = A@B1 -> f32 (for el/er) + bf16 (for gathers); C2 = A@B2 -> bf16 (res3).
__global__ __launch_bounds__(256) void k_gemm3(const float* __restrict__ A,
                                               const float* __restrict__ B1,
                                               const float* __restrict__ B2,
                                               float* __restrict__ C1f,
                                               unsigned short* __restrict__ C1b,
                                               unsigned short* __restrict__ C2b,
                                               int nrows) {
    __shared__ float At[128][65];
    __shared__ float Bs[64][68];
    const int t  = threadIdx.x;
    const int n0 = blockIdx.x * 64;
    const int r0 = (t & 15) * 4;
    const int c0 = (t >> 4) * 4;
    const int c4 = (t & 15) * 4;
    const int rr = t >> 4;

#pragma unroll
    for (int half = 0; half < 2; ++half)
#pragma unroll
        for (int p = 0; p < 4; ++p) {
            int row = p * 16 + rr;
            int gr  = n0 + row;
            float4 v = make_float4(0.f, 0.f, 0.f, 0.f);
            if (gr < nrows)
                v = *reinterpret_cast<const float4*>(A + (size_t)gr * 128 + half * 64 + c4);
            At[half * 64 + c4 + 0][row] = v.x;
            At[half * 64 + c4 + 1][row] = v.y;
            At[half * 64 + c4 + 2][row] = v.z;
            At[half * 64 + c4 + 3][row] = v.w;
        }

    for (int ct = 0; ct < 12; ++ct) {
        const float* B = (ct < 6) ? B1 : B2;
        const int cc = (ct < 6 ? ct : ct - 6) * 64;
        float acc[4][4];
#pragma unroll
        for (int i = 0; i < 4; ++i)
#pragma unroll
            for (int j = 0; j < 4; ++j) acc[i][j] = 0.f;

        for (int kt = 0; kt < 2; ++kt) {
            __syncthreads();
#pragma unroll
            for (int p = 0; p < 4; ++p) {
                int k = p * 16 + rr;
                *reinterpret_cast<float4*>(&Bs[k][c4]) =
                    *reinterpret_cast<const float4*>(B + (size_t)(kt * 64 + k) * 384 + cc + c4);
            }
            __syncthreads();
#pragma unroll 4
            for (int k = 0; k < 64; ++k) {
                float4 bv = *reinterpret_cast<const float4*>(&Bs[k][c0]);
                float a0 = At[kt * 64 + k][r0 + 0];
                float a1 = At[kt * 64 + k][r0 + 1];
                float a2 = At[kt * 64 + k][r0 + 2];
                float a3 = At[kt * 64 + k][r0 + 3];
                acc[0][0] = fmaf(a0, bv.x, acc[0][0]); acc[0][1] = fmaf(a0, bv.y, acc[0][1]);
                acc[0][2] = fmaf(a0, bv.z, acc[0][2]); acc[0][3] = fmaf(a0, bv.w, acc[0][3]);
                acc[1][0] = fmaf(a1, bv.x, acc[1][0]); acc[1][1] = fmaf(a1, bv.y, acc[1][1]);
                acc[1][2] = fmaf(a1, bv.z, acc[1][2]); acc[1][3] = fmaf(a1, bv.w, acc[1][3]);
                acc[2][0] = fmaf(a2, bv.x, acc[2][0]); acc[2][1] = fmaf(a2, bv.y, acc[2][1]);
                acc[2][2] = fmaf(a2, bv.z, acc[2][2]); acc[2][3] = fmaf(a2, bv.w, acc[2][3]);
                acc[3][0] = fmaf(a3, bv.x, acc[3][0]); acc[3][1] = fmaf(a3, bv.y, acc[3][1]);
                acc[3][2] = fmaf(a3, bv.z, acc[3][2]); acc[3][3] = fmaf(a3, bv.w, acc[3][3]);
            }
        }
#pragma unroll
        for (int i = 0; i < 4; ++i) {
            int gr = n0 + r0 + i;
            if (gr >= nrows) continue;
            unsigned u0 = f2bf(acc[i][0]) | (f2bf(acc[i][1]) << 16);
            unsigned u1 = f2bf(acc[i][2]) | (f2bf(acc[i][3]) << 16);
            if (ct < 6) {
                *reinterpret_cast<float4*>(C1f + (size_t)gr * 384 + cc + c0) =
                    make_float4(acc[i][0], acc[i][1], acc[i][2], acc[i][3]);
                *reinterpret_cast<uint2*>(C1b + (size_t)gr * 384 + cc + c0) = make_uint2(u0, u1);
            } else {
                *reinterpret_cast<uint2*>(C2b + (size_t)gr * 384 + cc + c0) = make_uint2(u0, u1);
            }
        }
    }
}

// ---------------------------------------------------------------- el / er
template <int H, int D>
__global__ void k_elr(const float* __restrict__ feat, const float* __restrict__ al,
                      const float* __restrict__ ar, float* __restrict__ el,
                      float* __restrict__ er, int total) {
    int gid = blockIdx.x * blockDim.x + threadIdx.x;
    if (gid >= total) return;
    int n = gid / H, h = gid - n * H;
    const float4* f = reinterpret_cast<const float4*>(feat + (size_t)n * (H * D) + h * D);
    const float4* a = reinterpret_cast<const float4*>(al + h * D);
    const float4* r = reinterpret_cast<const float4*>(ar + h * D);
    float sl = 0.f, sr = 0.f;
#pragma unroll
    for (int j = 0; j < D / 4; ++j) {
        float4 fv = f[j], av = a[j], rv = r[j];
        sl += fv.x * av.x + fv.y * av.y + fv.z * av.z + fv.w * av.w;
        sr += fv.x * rv.x + fv.y * rv.y + fv.z * rv.z + fv.w * rv.w;
    }
    el[gid] = sl;
    er[gid] = sr;
}

// ---------------------------------------------------------------- aggregation, F=128
// Online max-free softmax fused; lane owns features {lane, 64+lane}.
// res/out may alias (layer-2 in-place residual).
template <bool HASRES>
__global__ __launch_bounds__(256) void k_aggr128(
    const float* __restrict__ feat, const int* __restrict__ csr,
    const int* __restrict__ offs, const float* __restrict__ el,
    const float* __restrict__ er, const float* __restrict__ bias,
    const float* res, float* out, int nnodes) {
    int node = blockIdx.x * 4 + (threadIdx.x >> 6);
    if (node >= nnodes) return;
    int lane = threadIdx.x & 63;
    int h0 = lane >> 5;
    float er0 = er[node * 4 + h0];
    float er1 = er[node * 4 + 2 + h0];
    int o0 = offs[node], o1 = offs[node + 1];
    float acc0 = 0.f, acc1 = 0.f, s0 = 0.f, s1 = 0.f;
    int p = o0;
    for (; p + 1 < o1; p += 2) {
        int sa = csr[p], sb = csr[p + 1];
        const float* fa = feat + (size_t)sa * 128;
        const float* fb = feat + (size_t)sb * 128;
        float wa0 = __expf(leaky(el[sa * 4 + h0] + er0));
        float wa1 = __expf(leaky(el[sa * 4 + 2 + h0] + er1));
        float wb0 = __expf(leaky(el[sb * 4 + h0] + er0));
        float wb1 = __expf(leaky(el[sb * 4 + 2 + h0] + er1));
        s0 += wa0 + wb0;
        s1 += wa1 + wb1;
        acc0 = fmaf(wa0, fa[lane], acc0);
        acc0 = fmaf(wb0, fb[lane], acc0);
        acc1 = fmaf(wa1, fa[64 + lane], acc1);
        acc1 = fmaf(wb1, fb[64 + lane], acc1);
    }
    if (p < o1) {
        int sa = csr[p];
        const float* fa = feat + (size_t)sa * 128;
        float wa0 = __expf(leaky(el[sa * 4 + h0] + er0));
        float wa1 = __expf(leaky(el[sa * 4 + 2 + h0] + er1));
        s0 += wa0; s1 += wa1;
        acc0 = fmaf(wa0, fa[lane], acc0);
        acc1 = fmaf(wa1, fa[64 + lane], acc1);
    }
    float inv0 = (o1 > o0) ? 1.f / s0 : 0.f;
    float inv1 = (o1 > o0) ? 1.f / s1 : 0.f;
    float r0 = acc0 * inv0 + bias[lane]      + (HASRES ? res[(size_t)node * 128 + lane]      : 0.f);
    float r1 = acc1 * inv1 + bias[64 + lane] + (HASRES ? res[(size_t)node * 128 + 64 + lane] : 0.f);
    r0 = (r0 > 0.f) ? r0 : (__expf(r0) - 1.f);
    r1 = (r1 > 0.f) ? r1 : (__expf(r1) - 1.f);
    out[(size_t)node * 128 + lane]      = r0;
    out[(size_t)node * 128 + 64 + lane] = r1;
}

// ---------------------------------------------------------------- aggregation, F=384 (bf16 gathers)
__global__ __launch_bounds__(256) void k_aggr384(
    const unsigned short* __restrict__ feat, const int* __restrict__ csr,
    const int* __restrict__ offs, const float* __restrict__ el,
    const float* __restrict__ er, const float* __restrict__ b3,
    const unsigned short* __restrict__ res3, float* __restrict__ out, int nnodes) {
    int node = blockIdx.x * 4 + (threadIdx.x >> 6);
    if (node >= nnodes) return;
    int lane = threadIdx.x & 63;
    const float2* e2 = reinterpret_cast<const float2*>(er + (size_t)node * 6);
    float2 ex = e2[0], ey = e2[1], ez = e2[2];
    float erv[6] = {ex.x, ex.y, ey.x, ey.y, ez.x, ez.y};
    float acc[6] = {0.f, 0.f, 0.f, 0.f, 0.f, 0.f};
    float s[6]   = {0.f, 0.f, 0.f, 0.f, 0.f, 0.f};
    int o0 = offs[node], o1 = offs[node + 1];
    int p = o0;
    for (; p + 1 < o1; p += 2) {
        int sa = csr[p], sb = csr[p + 1];
        const unsigned short* fa = feat + (size_t)sa * 384;
        const unsigned short* fb = feat + (size_t)sb * 384;
        const float2* la = reinterpret_cast<const float2*>(el + (size_t)sa * 6);
        const float2* lb = reinterpret_cast<const float2*>(el + (size_t)sb * 6);
        float2 a0 = la[0], a1 = la[1], a2 = la[2];
        float2 b0 = lb[0], b1 = lb[1], b2 = lb[2];
        float ela[6] = {a0.x, a0.y, a1.x, a1.y, a2.x, a2.y};
        float elb[6] = {b0.x, b0.y, b1.x, b1.y, b2.x, b2.y};
#pragma unroll
        for (int b = 0; b < 6; ++b) {
            float wa = __expf(leaky(ela[b] + erv[b]));
            float wb = __expf(leaky(elb[b] + erv[b]));
            s[b] += wa + wb;
            acc[b] = fmaf(wa, bf2f(fa[b * 64 + lane]), acc[b]);
            acc[b] = fmaf(wb, bf2f(fb[b * 64 + lane]), acc[b]);
        }
    }
    if (p < o1) {
        int sa = csr[p];
        const unsigned short* fa = feat + (size_t)sa * 384;
        const float2* la = reinterpret_cast<const float2*>(el + (size_t)sa * 6);
        float2 a0 = la[0], a1 = la[1], a2 = la[2];
        float ela[6] = {a0.x, a0.y, a1.x, a1.y, a2.x, a2.y};
#pragma unroll
        for (int b = 0; b < 6; ++b) {
            float wa = __expf(leaky(ela[b] + erv[b]));
            s[b] += wa;
            acc[b] = fmaf(wa, bf2f(fa[b * 64 + lane]), acc[b]);
        }
    }
    bool has = o1 > o0;
    float sum = 0.f;
#pragma unroll
    for (int b = 0; b < 6; ++b) {
        float inv = has ? 1.f / s[b] : 0.f;
        sum += acc[b] * inv + bf2f(res3[(size_t)node * 384 + b * 64 + lane]) + b3[b * 64 + lane];
    }
    out[(size_t)node * 64 + lane] = sum * (1.f / 6.f);
}

// ---------------------------------------------------------------- launch
extern "C" void kernel_launch(void* const* d_in, const int* in_sizes, int n_in,
                              void* d_out, int out_size, void* d_ws, size_t ws_size,
                              hipStream_t stream) {
    const float* x     = (const float*)d_in[0];
    const int*   src   = (const int*)d_in[1];
    const int*   dst   = (const int*)d_in[2];
    const float* W1    = (const float*)d_in[3];
    const float* al1   = (const float*)d_in[4];
    const float* ar1   = (const float*)d_in[5];
    const float* b1    = (const float*)d_in[6];
    const float* W2    = (const float*)d_in[7];
    const float* al2   = (const float*)d_in[8];
    const float* ar2   = (const float*)d_in[9];
    const float* b2    = (const float*)d_in[10];
    const float* W3    = (const float*)d_in[11];
    const float* al3   = (const float*)d_in[12];
    const float* ar3   = (const float*)d_in[13];
    const float* b3    = (const float*)d_in[14];
    const float* Wres3 = (const float*)d_in[15];
    float* out = (float*)d_out;

    const int N = NODES, E = EDGES;

    char*  ws = (char*)d_ws;
    size_t o  = 0;
    auto alloc = [&](size_t bytes) {
        size_t r = o;
        o += (bytes + 255) & ~(size_t)255;
        return r;
    };
    int*            offs = (int*)(ws + alloc((size_t)(N + 1) * 4));
    int*            cnt  = (int*)(ws + alloc((size_t)N * 4));
    int*            csr  = (int*)(ws + alloc((size_t)E * 4));
    float*          el   = (float*)(ws + alloc((size_t)N * 6 * 4));
    float*          er   = (float*)(ws + alloc((size_t)N * 6 * 4));
    float*          bufA = (float*)(ws + alloc((size_t)N * 384 * 4));   // f32 proj feat
    float*          bufC = (float*)(ws + alloc((size_t)N * 128 * 4));   // h1 then h2
    unsigned short* bfA  = (unsigned short*)(ws + alloc((size_t)N * 384 * 2)); // bf16 feat3
    unsigned short* bfB  = (unsigned short*)(ws + alloc((size_t)N * 384 * 2)); // bf16 res3

    const int gE = (E + 255) / 256;
    const int g4 = (N * 4 + 255) / 256;
    const int g6 = (N * 6 + 255) / 256;
    const int gA = (N + 3) / 4;
    const int gG = (N + 63) / 64;

    // ---- CSR by dst
    hipMemsetAsync(cnt, 0, (size_t)N * 4, stream);
    k_hist<<<gE, 256, 0, stream>>>(dst, cnt, E);
    k_scan<<<1, 1024, 0, stream>>>(cnt, offs, N);
    hipMemsetAsync(cnt, 0, (size_t)N * 4, stream);
    k_fill<<<gE, 256, 0, stream>>>(src, dst, offs, cnt, csr, E);

    // ---- layer 1: x -> h1 (bufC)
    k_gemm128<<<gG, 256, 0, stream>>>(x, W1, bufA, N);
    k_elr<4, 32><<<g4, 256, 0, stream>>>(bufA, al1, ar1, el, er, N * 4);
    k_aggr128<false><<<gA, 256, 0, stream>>>(bufA, csr, offs, el, er, b1, nullptr, bufC, N);

    // ---- layer 2: h1 -> h2 (bufC in place; residual = h1)
    k_gemm128<<<gG, 256, 0, stream>>>(bufC, W2, bufA, N);
    k_elr<4, 32><<<g4, 256, 0, stream>>>(bufA, al2, ar2, el, er, N * 4);
    k_aggr128<true><<<gA, 256, 0, stream>>>(bufA, csr, offs, el, er, b2, bufC, bufC, N);

    // ---- layer 3: h2 -> out (fused dual GEMM; bf16 gathers; head-mean)
    k_gemm3<<<gG, 256, 0, stream>>>(bufC, W3, Wres3, bufA, bfA, bfB, N);
    k_elr<6, 64><<<g6, 256, 0, stream>>>(bufA, al3, ar3, el, er, N * 6);
    k_aggr384<<<gA, 256, 0, stream>>>(bfA, csr, offs, el, er, b3, bfB, out, N);
}

// Round 3
// 740.606 us; speedup vs baseline: 1.3172x; 1.0602x over previous
//
#include <hip/hip_runtime.h>
#include <hip/hip_bf16.h>

// DistGAT: 3-layer GAT, N=50000 nodes, E=800000 edges.
// R3: (1) GEMM LDS tiles padded to stride 68 -> aligned ds_read_b128 for A
//     fragment (was 4x scalar b32, LDS-bound at 33% VALUBusy),
//     (2) ALL feat buffers bf16 (layers 1-2 too): GEMM writes bf16 only,
//     el/er computed from bf16 feat, aggr128 gathers halve to 256 B/edge,
//     (3) aggr128 lane owns features {2*lane, 2*lane+1} (same head) -> one
//     uint gather + one weight per edge per lane.

#define NODES 50000
#define EDGES 800000
#define NEG 0.2f

__device__ __forceinline__ float leaky(float e) { return e > 0.f ? e : NEG * e; }
__device__ __forceinline__ float blo(unsigned u) { return __uint_as_float(u << 16); }
__device__ __forceinline__ float bhi(unsigned u) { return __uint_as_float(u & 0xffff0000u); }
__device__ __forceinline__ float bf2f(unsigned short u) {
    return __uint_as_float(((unsigned)u) << 16);
}
__device__ __forceinline__ unsigned f2bf(float f) {  // RNE, low 16 bits valid
    unsigned u = __float_as_uint(f);
    return (u + 0x7fffu + ((u >> 16) & 1u)) >> 16;
}
__device__ __forceinline__ float sel4(float4 v, int h) {  // v[h], static selects
    float a = (h & 1) ? v.y : v.x;
    float b = (h & 1) ? v.w : v.z;
    return (h & 2) ? b : a;
}

// ---------------------------------------------------------------- CSR build
__global__ void k_hist(const int* __restrict__ dst, int* __restrict__ cnt, int e) {
    int gid = blockIdx.x * blockDim.x + threadIdx.x;
    if (gid < e) atomicAdd(&cnt[dst[gid]], 1);
}

__global__ __launch_bounds__(1024) void k_scan(const int* __restrict__ deg,
                                               int* __restrict__ offs, int n) {
    const int CH = (n + 1023) / 1024;
    int t = threadIdx.x;
    int base = t * CH;
    int s = 0;
    for (int j = 0; j < CH; ++j) {
        int i = base + j;
        if (i < n) s += deg[i];
    }
    __shared__ int sm[1024];
    sm[t] = s;
    __syncthreads();
    for (int off = 1; off < 1024; off <<= 1) {
        int v = (t >= off) ? sm[t - off] : 0;
        __syncthreads();
        sm[t] += v;
        __syncthreads();
    }
    int run = sm[t] - s;
    for (int j = 0; j < CH; ++j) {
        int i = base + j;
        if (i < n) { offs[i] = run; run += deg[i]; }
    }
    if (t == 1023) offs[n] = sm[1023];
}

__global__ void k_fill(const int* __restrict__ src, const int* __restrict__ dst,
                       const int* __restrict__ offs, int* __restrict__ cur,
                       int* __restrict__ csr, int e) {
    int gid = blockIdx.x * blockDim.x + threadIdx.x;
    if (gid < e) {
        int d = dst[gid];
        int pos = offs[d] + atomicAdd(&cur[d], 1);
        csr[pos] = src[gid];
    }
}

// ---------------------------------------------------------------- GEMM, F=128 -> bf16
// C[N,128] = A[N,128] @ B[128,128]. Stride-68 tiles: aligned b128 reads,
// 2-way-max bank aliasing (272 B rows). A staged once per block.
__global__ __launch_bounds__(256) void k_gemm128b(const float* __restrict__ A,
                                                  const float* __restrict__ B,
                                                  unsigned short* __restrict__ Cb,
                                                  int nrows) {
    __shared__ float At[128][68];  // [k][row]
    __shared__ float Bs[64][68];   // [k][col]
    const int t  = threadIdx.x;
    const int n0 = blockIdx.x * 64;
    const int r0 = (t & 15) * 4;
    const int c0 = (t >> 4) * 4;
    const int c4 = (t & 15) * 4;
    const int rr = t >> 4;

#pragma unroll
    for (int half = 0; half < 2; ++half)
#pragma unroll
        for (int p = 0; p < 4; ++p) {
            int row = p * 16 + rr;
            int gr  = n0 + row;
            float4 v = make_float4(0.f, 0.f, 0.f, 0.f);
            if (gr < nrows)
                v = *reinterpret_cast<const float4*>(A + (size_t)gr * 128 + half * 64 + c4);
            At[half * 64 + c4 + 0][row] = v.x;
            At[half * 64 + c4 + 1][row] = v.y;
            At[half * 64 + c4 + 2][row] = v.z;
            At[half * 64 + c4 + 3][row] = v.w;
        }

    for (int ct = 0; ct < 2; ++ct) {
        float acc[4][4];
#pragma unroll
        for (int i = 0; i < 4; ++i)
#pragma unroll
            for (int j = 0; j < 4; ++j) acc[i][j] = 0.f;

        for (int kt = 0; kt < 2; ++kt) {
            __syncthreads();
#pragma unroll
            for (int p = 0; p < 4; ++p) {
                int k = p * 16 + rr;
                *reinterpret_cast<float4*>(&Bs[k][c4]) =
                    *reinterpret_cast<const float4*>(B + (size_t)(kt * 64 + k) * 128 + ct * 64 + c4);
            }
            __syncthreads();
#pragma unroll 2
            for (int k = 0; k < 64; ++k) {
                float4 bv = *reinterpret_cast<const float4*>(&Bs[k][c0]);
                float4 av = *reinterpret_cast<const float4*>(&At[kt * 64 + k][r0]);
                acc[0][0] = fmaf(av.x, bv.x, acc[0][0]); acc[0][1] = fmaf(av.x, bv.y, acc[0][1]);
                acc[0][2] = fmaf(av.x, bv.z, acc[0][2]); acc[0][3] = fmaf(av.x, bv.w, acc[0][3]);
                acc[1][0] = fmaf(av.y, bv.x, acc[1][0]); acc[1][1] = fmaf(av.y, bv.y, acc[1][1]);
                acc[1][2] = fmaf(av.y, bv.z, acc[1][2]); acc[1][3] = fmaf(av.y, bv.w, acc[1][3]);
                acc[2][0] = fmaf(av.z, bv.x, acc[2][0]); acc[2][1] = fmaf(av.z, bv.y, acc[2][1]);
                acc[2][2] = fmaf(av.z, bv.z, acc[2][2]); acc[2][3] = fmaf(av.z, bv.w, acc[2][3]);
                acc[3][0] = fmaf(av.w, bv.x, acc[3][0]); acc[3][1] = fmaf(av.w, bv.y, acc[3][1]);
                acc[3][2] = fmaf(av.w, bv.z, acc[3][2]); acc[3][3] = fmaf(av.w, bv.w, acc[3][3]);
            }
        }
#pragma unroll
        for (int i = 0; i < 4; ++i) {
            int gr = n0 + r0 + i;
            if (gr < nrows) {
                unsigned u0 = f2bf(acc[i][0]) | (f2bf(acc[i][1]) << 16);
                unsigned u1 = f2bf(acc[i][2]) | (f2bf(acc[i][3]) << 16);
                *reinterpret_cast<uint2*>(Cb + (size_t)gr * 128 + ct * 64 + c0) = make_uint2(u0, u1);
            }
        }
    }
}

// ---------------------------------------------------------------- GEMM, layer 3 fused -> bf16
__global__ __launch_bounds__(256) void k_gemm3(const float* __restrict__ A,
                                               const float* __restrict__ B1,
                                               const float* __restrict__ B2,
                                               unsigned short* __restrict__ C1b,
                                               unsigned short* __restrict__ C2b,
                                               int nrows) {
    __shared__ float At[128][68];
    __shared__ float Bs[64][68];
    const int t  = threadIdx.x;
    const int n0 = blockIdx.x * 64;
    const int r0 = (t & 15) * 4;
    const int c0 = (t >> 4) * 4;
    const int c4 = (t & 15) * 4;
    const int rr = t >> 4;

#pragma unroll
    for (int half = 0; half < 2; ++half)
#pragma unroll
        for (int p = 0; p < 4; ++p) {
            int row = p * 16 + rr;
            int gr  = n0 + row;
            float4 v = make_float4(0.f, 0.f, 0.f, 0.f);
            if (gr < nrows)
                v = *reinterpret_cast<const float4*>(A + (size_t)gr * 128 + half * 64 + c4);
            At[half * 64 + c4 + 0][row] = v.x;
            At[half * 64 + c4 + 1][row] = v.y;
            At[half * 64 + c4 + 2][row] = v.z;
            At[half * 64 + c4 + 3][row] = v.w;
        }

    for (int ct = 0; ct < 12; ++ct) {
        const float* B = (ct < 6) ? B1 : B2;
        const int cc = (ct < 6 ? ct : ct - 6) * 64;
        float acc[4][4];
#pragma unroll
        for (int i = 0; i < 4; ++i)
#pragma unroll
            for (int j = 0; j < 4; ++j) acc[i][j] = 0.f;

        for (int kt = 0; kt < 2; ++kt) {
            __syncthreads();
#pragma unroll
            for (int p = 0; p < 4; ++p) {
                int k = p * 16 + rr;
                *reinterpret_cast<float4*>(&Bs[k][c4]) =
                    *reinterpret_cast<const float4*>(B + (size_t)(kt * 64 + k) * 384 + cc + c4);
            }
            __syncthreads();
#pragma unroll 2
            for (int k = 0; k < 64; ++k) {
                float4 bv = *reinterpret_cast<const float4*>(&Bs[k][c0]);
                float4 av = *reinterpret_cast<const float4*>(&At[kt * 64 + k][r0]);
                acc[0][0] = fmaf(av.x, bv.x, acc[0][0]); acc[0][1] = fmaf(av.x, bv.y, acc[0][1]);
                acc[0][2] = fmaf(av.x, bv.z, acc[0][2]); acc[0][3] = fmaf(av.x, bv.w, acc[0][3]);
                acc[1][0] = fmaf(av.y, bv.x, acc[1][0]); acc[1][1] = fmaf(av.y, bv.y, acc[1][1]);
                acc[1][2] = fmaf(av.y, bv.z, acc[1][2]); acc[1][3] = fmaf(av.y, bv.w, acc[1][3]);
                acc[2][0] = fmaf(av.z, bv.x, acc[2][0]); acc[2][1] = fmaf(av.z, bv.y, acc[2][1]);
                acc[2][2] = fmaf(av.z, bv.z, acc[2][2]); acc[2][3] = fmaf(av.z, bv.w, acc[2][3]);
                acc[3][0] = fmaf(av.w, bv.x, acc[3][0]); acc[3][1] = fmaf(av.w, bv.y, acc[3][1]);
                acc[3][2] = fmaf(av.w, bv.z, acc[3][2]); acc[3][3] = fmaf(av.w, bv.w, acc[3][3]);
            }
        }
        unsigned short* Cb = (ct < 6) ? C1b : C2b;
#pragma unroll
        for (int i = 0; i < 4; ++i) {
            int gr = n0 + r0 + i;
            if (gr < nrows) {
                unsigned u0 = f2bf(acc[i][0]) | (f2bf(acc[i][1]) << 16);
                unsigned u1 = f2bf(acc[i][2]) | (f2bf(acc[i][3]) << 16);
                *reinterpret_cast<uint2*>(Cb + (size_t)gr * 384 + cc + c0) = make_uint2(u0, u1);
            }
        }
    }
}

// ---------------------------------------------------------------- el / er from bf16 feat
template <int H, int D>
__global__ void k_elr_bf(const unsigned short* __restrict__ feat,
                         const float* __restrict__ al, const float* __restrict__ ar,
                         float* __restrict__ el, float* __restrict__ er, int total) {
    int gid = blockIdx.x * blockDim.x + threadIdx.x;
    if (gid >= total) return;
    int n = gid / H, h = gid - n * H;
    const uint4* f = reinterpret_cast<const uint4*>(feat + (size_t)n * (H * D) + h * D);
    const float4* a = reinterpret_cast<const float4*>(al + h * D);
    const float4* r = reinterpret_cast<const float4*>(ar + h * D);
    float sl = 0.f, sr = 0.f;
#pragma unroll
    for (int j = 0; j < D / 8; ++j) {
        uint4 v = f[j];
        float4 a0 = a[2 * j], a1 = a[2 * j + 1];
        float4 r0 = r[2 * j], r1 = r[2 * j + 1];
        float x0 = blo(v.x), x1 = bhi(v.x), x2 = blo(v.y), x3 = bhi(v.y);
        float x4 = blo(v.z), x5 = bhi(v.z), x6 = blo(v.w), x7 = bhi(v.w);
        sl += x0 * a0.x + x1 * a0.y + x2 * a0.z + x3 * a0.w +
              x4 * a1.x + x5 * a1.y + x6 * a1.z + x7 * a1.w;
        sr += x0 * r0.x + x1 * r0.y + x2 * r0.z + x3 * r0.w +
              x4 * r1.x + x5 * r1.y + x6 * r1.z + x7 * r1.w;
    }
    el[gid] = sl;
    er[gid] = sr;
}

// ---------------------------------------------------------------- aggregation, F=128, bf16
// Lane owns features {2*lane, 2*lane+1} (same head h0=lane>>4): one uint gather
// + one weight per edge. res/out may alias (layer-2 in-place residual).
template <bool HASRES>
__global__ __launch_bounds__(256) void k_aggr128b(
    const unsigned short* __restrict__ feat, const int* __restrict__ csr,
    const int* __restrict__ offs, const float* __restrict__ el,
    const float* __restrict__ er, const float* __restrict__ bias,
    const float* res, float* out, int nnodes) {
    int node = blockIdx.x * 4 + (threadIdx.x >> 6);
    if (node >= nnodes) return;
    int lane = threadIdx.x & 63;
    int f0 = lane * 2;
    int h0 = lane >> 4;
    float4 ern = *reinterpret_cast<const float4*>(er + (size_t)node * 4);
    float erh = sel4(ern, h0);
    int o0 = offs[node], o1 = offs[node + 1];
    float acc0 = 0.f, acc1 = 0.f, s = 0.f;
    int p = o0;
    for (; p + 1 < o1; p += 2) {
        int sa = csr[p], sb = csr[p + 1];
        float4 la = *reinterpret_cast<const float4*>(el + (size_t)sa * 4);
        float4 lb = *reinterpret_cast<const float4*>(el + (size_t)sb * 4);
        unsigned ua = *reinterpret_cast<const unsigned*>(feat + (size_t)sa * 128 + f0);
        unsigned ub = *reinterpret_cast<const unsigned*>(feat + (size_t)sb * 128 + f0);
        float wa = __expf(leaky(sel4(la, h0) + erh));
        float wb = __expf(leaky(sel4(lb, h0) + erh));
        s += wa + wb;
        acc0 = fmaf(wa, blo(ua), acc0);
        acc1 = fmaf(wa, bhi(ua), acc1);
        acc0 = fmaf(wb, blo(ub), acc0);
        acc1 = fmaf(wb, bhi(ub), acc1);
    }
    if (p < o1) {
        int sa = csr[p];
        float4 la = *reinterpret_cast<const float4*>(el + (size_t)sa * 4);
        unsigned ua = *reinterpret_cast<const unsigned*>(feat + (size_t)sa * 128 + f0);
        float wa = __expf(leaky(sel4(la, h0) + erh));
        s += wa;
        acc0 = fmaf(wa, blo(ua), acc0);
        acc1 = fmaf(wa, bhi(ua), acc1);
    }
    float inv = (o1 > o0) ? 1.f / s : 0.f;
    float2 bi = *reinterpret_cast<const float2*>(bias + f0);
    float rx = acc0 * inv + bi.x;
    float ry = acc1 * inv + bi.y;
    if (HASRES) {
        float2 rv = *reinterpret_cast<const float2*>(res + (size_t)node * 128 + f0);
        rx += rv.x;
        ry += rv.y;
    }
    rx = (rx > 0.f) ? rx : (__expf(rx) - 1.f);
    ry = (ry > 0.f) ? ry : (__expf(ry) - 1.f);
    *reinterpret_cast<float2*>(out + (size_t)node * 128 + f0) = make_float2(rx, ry);
}

// ---------------------------------------------------------------- aggregation, F=384 (bf16)
__global__ __launch_bounds__(256) void k_aggr384(
    const unsigned short* __restrict__ feat, const int* __restrict__ csr,
    const int* __restrict__ offs, const float* __restrict__ el,
    const float* __restrict__ er, const float* __restrict__ b3,
    const unsigned short* __restrict__ res3, float* __restrict__ out, int nnodes) {
    int node = blockIdx.x * 4 + (threadIdx.x >> 6);
    if (node >= nnodes) return;
    int lane = threadIdx.x & 63;
    const float2* e2 = reinterpret_cast<const float2*>(er + (size_t)node * 6);
    float2 ex = e2[0], ey = e2[1], ez = e2[2];
    float erv[6] = {ex.x, ex.y, ey.x, ey.y, ez.x, ez.y};
    float acc[6] = {0.f, 0.f, 0.f, 0.f, 0.f, 0.f};
    float s[6]   = {0.f, 0.f, 0.f, 0.f, 0.f, 0.f};
    int o0 = offs[node], o1 = offs[node + 1];
    int p = o0;
    for (; p + 1 < o1; p += 2) {
        int sa = csr[p], sb = csr[p + 1];
        const unsigned short* fa = feat + (size_t)sa * 384;
        const unsigned short* fb = feat + (size_t)sb * 384;
        const float2* la = reinterpret_cast<const float2*>(el + (size_t)sa * 6);
        const float2* lb = reinterpret_cast<const float2*>(el + (size_t)sb * 6);
        float2 a0 = la[0], a1 = la[1], a2 = la[2];
        float2 b0 = lb[0], b1 = lb[1], b2 = lb[2];
        float ela[6] = {a0.x, a0.y, a1.x, a1.y, a2.x, a2.y};
        float elb[6] = {b0.x, b0.y, b1.x, b1.y, b2.x, b2.y};
#pragma unroll
        for (int b = 0; b < 6; ++b) {
            float wa = __expf(leaky(ela[b] + erv[b]));
            float wb = __expf(leaky(elb[b] + erv[b]));
            s[b] += wa + wb;
            acc[b] = fmaf(wa, bf2f(fa[b * 64 + lane]), acc[b]);
            acc[b] = fmaf(wb, bf2f(fb[b * 64 + lane]), acc[b]);
        }
    }
    if (p < o1) {
        int sa = csr[p];
        const unsigned short* fa = feat + (size_t)sa * 384;
        const float2* la = reinterpret_cast<const float2*>(el + (size_t)sa * 6);
        float2 a0 = la[0], a1 = la[1], a2 = la[2];
        float ela[6] = {a0.x, a0.y, a1.x, a1.y, a2.x, a2.y};
#pragma unroll
        for (int b = 0; b < 6; ++b) {
            float wa = __expf(leaky(ela[b] + erv[b]));
            s[b] += wa;
            acc[b] = fmaf(wa, bf2f(fa[b * 64 + lane]), acc[b]);
        }
    }
    bool has = o1 > o0;
    float sum = 0.f;
#pragma unroll
    for (int b = 0; b < 6; ++b) {
        float inv = has ? 1.f / s[b] : 0.f;
        sum += acc[b] * inv + bf2f(res3[(size_t)node * 384 + b * 64 + lane]) + b3[b * 64 + lane];
    }
    out[(size_t)node * 64 + lane] = sum * (1.f / 6.f);
}

// ---------------------------------------------------------------- launch
extern "C" void kernel_launch(void* const* d_in, const int* in_sizes, int n_in,
                              void* d_out, int out_size, void* d_ws, size_t ws_size,
                              hipStream_t stream) {
    const float* x     = (const float*)d_in[0];
    const int*   src   = (const int*)d_in[1];
    const int*   dst   = (const int*)d_in[2];
    const float* W1    = (const float*)d_in[3];
    const float* al1   = (const float*)d_in[4];
    const float* ar1   = (const float*)d_in[5];
    const float* b1    = (const float*)d_in[6];
    const float* W2    = (const float*)d_in[7];
    const float* al2   = (const float*)d_in[8];
    const float* ar2   = (const float*)d_in[9];
    const float* b2    = (const float*)d_in[10];
    const float* W3    = (const float*)d_in[11];
    const float* al3   = (const float*)d_in[12];
    const float* ar3   = (const float*)d_in[13];
    const float* b3    = (const float*)d_in[14];
    const float* Wres3 = (const float*)d_in[15];
    float* out = (float*)d_out;

    const int N = NODES, E = EDGES;

    char*  ws = (char*)d_ws;
    size_t o  = 0;
    auto alloc = [&](size_t bytes) {
        size_t r = o;
        o += (bytes + 255) & ~(size_t)255;
        return r;
    };
    int*            offs = (int*)(ws + alloc((size_t)(N + 1) * 4));
    int*            cnt  = (int*)(ws + alloc((size_t)N * 4));
    int*            csr  = (int*)(ws + alloc((size_t)E * 4));
    float*          el   = (float*)(ws + alloc((size_t)N * 6 * 4));
    float*          er   = (float*)(ws + alloc((size_t)N * 6 * 4));
    unsigned short* bf1  = (unsigned short*)(ws + alloc((size_t)N * 128 * 2)); // bf16 feat L1/L2
    float*          bufC = (float*)(ws + alloc((size_t)N * 128 * 4));          // h1 then h2 (f32)
    unsigned short* bfA  = (unsigned short*)(ws + alloc((size_t)N * 384 * 2)); // bf16 feat3
    unsigned short* bfB  = (unsigned short*)(ws + alloc((size_t)N * 384 * 2)); // bf16 res3

    const int gE = (E + 255) / 256;
    const int g4 = (N * 4 + 255) / 256;
    const int g6 = (N * 6 + 255) / 256;
    const int gA = (N + 3) / 4;
    const int gG = (N + 63) / 64;

    // ---- CSR by dst
    hipMemsetAsync(cnt, 0, (size_t)N * 4, stream);
    k_hist<<<gE, 256, 0, stream>>>(dst, cnt, E);
    k_scan<<<1, 1024, 0, stream>>>(cnt, offs, N);
    hipMemsetAsync(cnt, 0, (size_t)N * 4, stream);
    k_fill<<<gE, 256, 0, stream>>>(src, dst, offs, cnt, csr, E);

    // ---- layer 1: x -> h1 (bufC f32)
    k_gemm128b<<<gG, 256, 0, stream>>>(x, W1, bf1, N);
    k_elr_bf<4, 32><<<g4, 256, 0, stream>>>(bf1, al1, ar1, el, er, N * 4);
    k_aggr128b<false><<<gA, 256, 0, stream>>>(bf1, csr, offs, el, er, b1, nullptr, bufC, N);

    // ---- layer 2: h1 -> h2 (bufC in place; residual = h1)
    k_gemm128b<<<gG, 256, 0, stream>>>(bufC, W2, bf1, N);
    k_elr_bf<4, 32><<<g4, 256, 0, stream>>>(bf1, al2, ar2, el, er, N * 4);
    k_aggr128b<true><<<gA, 256, 0, stream>>>(bf1, csr, offs, el, er, b2, bufC, bufC, N);

    // ---- layer 3: h2 -> out (fused dual GEMM -> bf16; head-mean)
    k_gemm3<<<gG, 256, 0, stream>>>(bufC, W3, Wres3, bfA, bfB, N);
    k_elr_bf<6, 64><<<g6, 256, 0, stream>>>(bfA, al3, ar3, el, er, N * 6);
    k_aggr384<<<gA, 256, 0, stream>>>(bfA, csr, offs, el, er, b3, bfB, out, N);
}

// Round 5
// 505.961 us; speedup vs baseline: 1.9280x; 1.4638x over previous
//
#include <hip/hip_runtime.h>
#include <hip/hip_bf16.h>

// DistGAT: 3-layer GAT, N=50000 nodes, E=800000 edges.
// R5: R4 (bf16 MFMA projections) + epilogue column fix: store col must include
//     the wave's cbase (was cb+n*16+lr, dropping cols 32-63 of every tile onto
//     cols 0-31 -> absmax 1.54). Everything else identical to R4.

#define NODES 50000
#define EDGES 800000
#define NEG 0.2f

typedef __attribute__((ext_vector_type(8))) short bh8;
typedef __attribute__((ext_vector_type(4))) float f4;

__device__ __forceinline__ float leaky(float e) { return e > 0.f ? e : NEG * e; }
__device__ __forceinline__ float blo(unsigned u) { return __uint_as_float(u << 16); }
__device__ __forceinline__ float bhi(unsigned u) { return __uint_as_float(u & 0xffff0000u); }
__device__ __forceinline__ float bf2f(unsigned short u) {
    return __uint_as_float(((unsigned)u) << 16);
}
__device__ __forceinline__ unsigned f2bf(float f) {  // RNE, low 16 bits valid
    unsigned u = __float_as_uint(f);
    return (u + 0x7fffu + ((u >> 16) & 1u)) >> 16;
}
__device__ __forceinline__ float sel4(float4 v, int h) {
    float a = (h & 1) ? v.y : v.x;
    float b = (h & 1) ? v.w : v.z;
    return (h & 2) ? b : a;
}

// swizzled byte offset in a [64][128-bf16] LDS tile (row stride 256 B)
#define SW(row, bc) (((row) << 8) + ((bc) ^ (((row) & 7) << 4)))

// ---------------------------------------------------------------- prep
__global__ void k_cast(const float* __restrict__ in, unsigned short* __restrict__ outb, int n4) {
    int gid = blockIdx.x * blockDim.x + threadIdx.x;
    if (gid >= n4) return;
    float4 v = *reinterpret_cast<const float4*>(in + (size_t)gid * 4);
    unsigned u0 = f2bf(v.x) | (f2bf(v.y) << 16);
    unsigned u1 = f2bf(v.z) | (f2bf(v.w) << 16);
    *reinterpret_cast<uint2*>(outb + (size_t)gid * 4) = make_uint2(u0, u1);
}

// W[k][f] f32 (k=128 rows, F cols) -> WT[f][128] bf16
__global__ void k_prepw(const float* __restrict__ W, unsigned short* __restrict__ WT, int F) {
    int gid = blockIdx.x * blockDim.x + threadIdx.x;
    if (gid >= 128 * F) return;
    int k = gid / F, f = gid - k * F;
    WT[(size_t)f * 128 + k] = (unsigned short)f2bf(W[gid]);
}

// ---------------------------------------------------------------- CSR build
__global__ void k_hist(const int* __restrict__ dst, int* __restrict__ cnt, int e) {
    int gid = blockIdx.x * blockDim.x + threadIdx.x;
    if (gid < e) atomicAdd(&cnt[dst[gid]], 1);
}

__global__ __launch_bounds__(1024) void k_scan(const int* __restrict__ deg,
                                               int* __restrict__ offs, int n) {
    const int CH = (n + 1023) / 1024;
    int t = threadIdx.x;
    int base = t * CH;
    int s = 0;
    for (int j = 0; j < CH; ++j) {
        int i = base + j;
        if (i < n) s += deg[i];
    }
    __shared__ int sm[1024];
    sm[t] = s;
    __syncthreads();
    for (int off = 1; off < 1024; off <<= 1) {
        int v = (t >= off) ? sm[t - off] : 0;
        __syncthreads();
        sm[t] += v;
        __syncthreads();
    }
    int run = sm[t] - s;
    for (int j = 0; j < CH; ++j) {
        int i = base + j;
        if (i < n) { offs[i] = run; run += deg[i]; }
    }
    if (t == 1023) offs[n] = sm[1023];
}

__global__ void k_fill(const int* __restrict__ src, const int* __restrict__ dst,
                       const int* __restrict__ offs, int* __restrict__ cur,
                       int* __restrict__ csr, int e) {
    int gid = blockIdx.x * blockDim.x + threadIdx.x;
    if (gid < e) {
        int d = dst[gid];
        int pos = offs[d] + atomicAdd(&cur[d], 1);
        csr[pos] = src[gid];
    }
}

// ---------------------------------------------------------------- MFMA GEMM
// C[M,F] = A[M,128] @ B[128,F], A bf16 row-major, BT bf16 [F][128].
// 64x64 tile per ct; 4 waves, each 32x32 (2x2 frags of 16x16x32).
// F=128: all cols -> C0 (width 128). F=768: ct<6 -> C0 (width 384, feat3),
// ct>=6 -> C1 (width 384, res3).
template <int F>
__global__ __launch_bounds__(256) void k_mgemm(const unsigned short* __restrict__ A,
                                               const unsigned short* __restrict__ BT,
                                               unsigned short* __restrict__ C0,
                                               unsigned short* __restrict__ C1,
                                               int nrows) {
    __shared__ char Alds[64 * 256];
    __shared__ char Blds[64 * 256];
    const int t  = threadIdx.x;
    const int n0 = blockIdx.x * 64;
    const int w  = t >> 6;
    const int l  = t & 63;
    const int lr = l & 15;
    const int lk = l >> 4;

    // stage A once: 64 rows x 128 bf16
    {
        int col8 = (t & 15) * 8;
        int bc   = col8 * 2;
#pragma unroll
        for (int p = 0; p < 4; ++p) {
            int row = p * 16 + (t >> 4);
            int gr  = n0 + row;
            uint4 v = make_uint4(0, 0, 0, 0);
            if (gr < nrows) v = *reinterpret_cast<const uint4*>(A + (size_t)gr * 128 + col8);
            *reinterpret_cast<uint4*>(Alds + SW(row, bc)) = v;
        }
    }

    const int rbase = (w & 1) * 32;
    const int cbase = (w >> 1) * 32;

    for (int ct = 0; ct < F / 64; ++ct) {
        __syncthreads();
        {   // stage BT rows [ct*64, ct*64+64)
            int col8 = (t & 15) * 8;
            int bc   = col8 * 2;
#pragma unroll
            for (int p = 0; p < 4; ++p) {
                int row = p * 16 + (t >> 4);
                uint4 v = *reinterpret_cast<const uint4*>(BT + (size_t)(ct * 64 + row) * 128 + col8);
                *reinterpret_cast<uint4*>(Blds + SW(row, bc)) = v;
            }
        }
        __syncthreads();

        f4 acc00 = {0.f, 0.f, 0.f, 0.f}, acc01 = {0.f, 0.f, 0.f, 0.f};
        f4 acc10 = {0.f, 0.f, 0.f, 0.f}, acc11 = {0.f, 0.f, 0.f, 0.f};
#pragma unroll
        for (int kk = 0; kk < 4; ++kk) {
            int bck = kk * 64 + lk * 16;
            bh8 a0 = *reinterpret_cast<const bh8*>(Alds + SW(rbase + lr, bck));
            bh8 a1 = *reinterpret_cast<const bh8*>(Alds + SW(rbase + 16 + lr, bck));
            bh8 b0 = *reinterpret_cast<const bh8*>(Blds + SW(cbase + lr, bck));
            bh8 b1 = *reinterpret_cast<const bh8*>(Blds + SW(cbase + 16 + lr, bck));
            acc00 = __builtin_amdgcn_mfma_f32_16x16x32_bf16(a0, b0, acc00, 0, 0, 0);
            acc01 = __builtin_amdgcn_mfma_f32_16x16x32_bf16(a0, b1, acc01, 0, 0, 0);
            acc10 = __builtin_amdgcn_mfma_f32_16x16x32_bf16(a1, b0, acc10, 0, 0, 0);
            acc11 = __builtin_amdgcn_mfma_f32_16x16x32_bf16(a1, b1, acc11, 0, 0, 0);
        }

        // epilogue: C row = (lane>>4)*4 + reg, col = lane&15  [verified mapping]
        // col MUST include the wave's cbase (R4 bug: it was omitted).
        unsigned short* dst = (F == 128) ? C0 : (ct < 6 ? C0 : C1);
        const int width  = (F == 128) ? 128 : 384;
        const int cb     = (F == 128) ? ct * 64 : (ct < 6 ? ct * 64 : ct * 64 - 384);
        const f4* accs[4] = {&acc00, &acc01, &acc10, &acc11};
#pragma unroll
        for (int m = 0; m < 2; ++m) {
#pragma unroll
            for (int j = 0; j < 4; ++j) {
                int gr = n0 + rbase + m * 16 + lk * 4 + j;
                if (gr >= nrows) continue;
#pragma unroll
                for (int n = 0; n < 2; ++n) {
                    float v = (*accs[m * 2 + n])[j];
                    dst[(size_t)gr * width + cb + cbase + n * 16 + lr] = (unsigned short)f2bf(v);
                }
            }
        }
    }
}

// ---------------------------------------------------------------- el / er from bf16 feat
template <int H, int D>
__global__ void k_elr_bf(const unsigned short* __restrict__ feat,
                         const float* __restrict__ al, const float* __restrict__ ar,
                         float* __restrict__ el, float* __restrict__ er, int total) {
    int gid = blockIdx.x * blockDim.x + threadIdx.x;
    if (gid >= total) return;
    int n = gid / H, h = gid - n * H;
    const uint4* f = reinterpret_cast<const uint4*>(feat + (size_t)n * (H * D) + h * D);
    const float4* a = reinterpret_cast<const float4*>(al + h * D);
    const float4* r = reinterpret_cast<const float4*>(ar + h * D);
    float sl = 0.f, sr = 0.f;
#pragma unroll
    for (int j = 0; j < D / 8; ++j) {
        uint4 v = f[j];
        float4 a0 = a[2 * j], a1 = a[2 * j + 1];
        float4 r0 = r[2 * j], r1 = r[2 * j + 1];
        float x0 = blo(v.x), x1 = bhi(v.x), x2 = blo(v.y), x3 = bhi(v.y);
        float x4 = blo(v.z), x5 = bhi(v.z), x6 = blo(v.w), x7 = bhi(v.w);
        sl += x0 * a0.x + x1 * a0.y + x2 * a0.z + x3 * a0.w +
              x4 * a1.x + x5 * a1.y + x6 * a1.z + x7 * a1.w;
        sr += x0 * r0.x + x1 * r0.y + x2 * r0.z + x3 * r0.w +
              x4 * r1.x + x5 * r1.y + x6 * r1.z + x7 * r1.w;
    }
    el[gid] = sl;
    er[gid] = sr;
}

// ---------------------------------------------------------------- aggregation, F=128, bf16
// Lane owns features {2*lane, 2*lane+1} (head h0=lane>>4). Writes bf16 h (for
// next GEMM); optionally also f32 h (layer-2 residual source).
template <bool HASRES, bool WRITEF32>
__global__ __launch_bounds__(256) void k_aggr128b(
    const unsigned short* __restrict__ feat, const int* __restrict__ csr,
    const int* __restrict__ offs, const float* __restrict__ el,
    const float* __restrict__ er, const float* __restrict__ bias,
    const float* __restrict__ resf, unsigned short* __restrict__ outb,
    float* __restrict__ outf, int nnodes) {
    int node = blockIdx.x * 4 + (threadIdx.x >> 6);
    if (node >= nnodes) return;
    int lane = threadIdx.x & 63;
    int f0 = lane * 2;
    int h0 = lane >> 4;
    float4 ern = *reinterpret_cast<const float4*>(er + (size_t)node * 4);
    float erh = sel4(ern, h0);
    int o0 = offs[node], o1 = offs[node + 1];
    float acc0 = 0.f, acc1 = 0.f, s = 0.f;
    int p = o0;
    for (; p + 1 < o1; p += 2) {
        int sa = csr[p], sb = csr[p + 1];
        float4 la = *reinterpret_cast<const float4*>(el + (size_t)sa * 4);
        float4 lb = *reinterpret_cast<const float4*>(el + (size_t)sb * 4);
        unsigned ua = *reinterpret_cast<const unsigned*>(feat + (size_t)sa * 128 + f0);
        unsigned ub = *reinterpret_cast<const unsigned*>(feat + (size_t)sb * 128 + f0);
        float wa = __expf(leaky(sel4(la, h0) + erh));
        float wb = __expf(leaky(sel4(lb, h0) + erh));
        s += wa + wb;
        acc0 = fmaf(wa, blo(ua), acc0);
        acc1 = fmaf(wa, bhi(ua), acc1);
        acc0 = fmaf(wb, blo(ub), acc0);
        acc1 = fmaf(wb, bhi(ub), acc1);
    }
    if (p < o1) {
        int sa = csr[p];
        float4 la = *reinterpret_cast<const float4*>(el + (size_t)sa * 4);
        unsigned ua = *reinterpret_cast<const unsigned*>(feat + (size_t)sa * 128 + f0);
        float wa = __expf(leaky(sel4(la, h0) + erh));
        s += wa;
        acc0 = fmaf(wa, blo(ua), acc0);
        acc1 = fmaf(wa, bhi(ua), acc1);
    }
    float inv = (o1 > o0) ? 1.f / s : 0.f;
    float2 bi = *reinterpret_cast<const float2*>(bias + f0);
    float rx = acc0 * inv + bi.x;
    float ry = acc1 * inv + bi.y;
    if (HASRES) {
        float2 rv = *reinterpret_cast<const float2*>(resf + (size_t)node * 128 + f0);
        rx += rv.x;
        ry += rv.y;
    }
    rx = (rx > 0.f) ? rx : (__expf(rx) - 1.f);
    ry = (ry > 0.f) ? ry : (__expf(ry) - 1.f);
    unsigned u = f2bf(rx) | (f2bf(ry) << 16);
    *reinterpret_cast<unsigned*>(outb + (size_t)node * 128 + f0) = u;
    if (WRITEF32)
        *reinterpret_cast<float2*>(outf + (size_t)node * 128 + f0) = make_float2(rx, ry);
}

// ---------------------------------------------------------------- aggregation, F=384 (bf16)
__global__ __launch_bounds__(256) void k_aggr384(
    const unsigned short* __restrict__ feat, const int* __restrict__ csr,
    const int* __restrict__ offs, const float* __restrict__ el,
    const float* __restrict__ er, const float* __restrict__ b3,
    const unsigned short* __restrict__ res3, float* __restrict__ out, int nnodes) {
    int node = blockIdx.x * 4 + (threadIdx.x >> 6);
    if (node >= nnodes) return;
    int lane = threadIdx.x & 63;
    const float2* e2 = reinterpret_cast<const float2*>(er + (size_t)node * 6);
    float2 ex = e2[0], ey = e2[1], ez = e2[2];
    float erv[6] = {ex.x, ex.y, ey.x, ey.y, ez.x, ez.y};
    float acc[6] = {0.f, 0.f, 0.f, 0.f, 0.f, 0.f};
    float s[6]   = {0.f, 0.f, 0.f, 0.f, 0.f, 0.f};
    int o0 = offs[node], o1 = offs[node + 1];
    int p = o0;
    for (; p + 1 < o1; p += 2) {
        int sa = csr[p], sb = csr[p + 1];
        const unsigned short* fa = feat + (size_t)sa * 384;
        const unsigned short* fb = feat + (size_t)sb * 384;
        const float2* la = reinterpret_cast<const float2*>(el + (size_t)sa * 6);
        const float2* lb = reinterpret_cast<const float2*>(el + (size_t)sb * 6);
        float2 a0 = la[0], a1 = la[1], a2 = la[2];
        float2 b0 = lb[0], b1 = lb[1], b2 = lb[2];
        float ela[6] = {a0.x, a0.y, a1.x, a1.y, a2.x, a2.y};
        float elb[6] = {b0.x, b0.y, b1.x, b1.y, b2.x, b2.y};
#pragma unroll
        for (int b = 0; b < 6; ++b) {
            float wa = __expf(leaky(ela[b] + erv[b]));
            float wb = __expf(leaky(elb[b] + erv[b]));
            s[b] += wa + wb;
            acc[b] = fmaf(wa, bf2f(fa[b * 64 + lane]), acc[b]);
            acc[b] = fmaf(wb, bf2f(fb[b * 64 + lane]), acc[b]);
        }
    }
    if (p < o1) {
        int sa = csr[p];
        const unsigned short* fa = feat + (size_t)sa * 384;
        const float2* la = reinterpret_cast<const float2*>(el + (size_t)sa * 6);
        float2 a0 = la[0], a1 = la[1], a2 = la[2];
        float ela[6] = {a0.x, a0.y, a1.x, a1.y, a2.x, a2.y};
#pragma unroll
        for (int b = 0; b < 6; ++b) {
            float wa = __expf(leaky(ela[b] + erv[b]));
            s[b] += wa;
            acc[b] = fmaf(wa, bf2f(fa[b * 64 + lane]), acc[b]);
        }
    }
    bool has = o1 > o0;
    float sum = 0.f;
#pragma unroll
    for (int b = 0; b < 6; ++b) {
        float inv = has ? 1.f / s[b] : 0.f;
        sum += acc[b] * inv + bf2f(res3[(size_t)node * 384 + b * 64 + lane]) + b3[b * 64 + lane];
    }
    out[(size_t)node * 64 + lane] = sum * (1.f / 6.f);
}

// ---------------------------------------------------------------- launch
extern "C" void kernel_launch(void* const* d_in, const int* in_sizes, int n_in,
                              void* d_out, int out_size, void* d_ws, size_t ws_size,
                              hipStream_t stream) {
    const float* x     = (const float*)d_in[0];
    const int*   src   = (const int*)d_in[1];
    const int*   dst   = (const int*)d_in[2];
    const float* W1    = (const float*)d_in[3];
    const float* al1   = (const float*)d_in[4];
    const float* ar1   = (const float*)d_in[5];
    const float* b1    = (const float*)d_in[6];
    const float* W2    = (const float*)d_in[7];
    const float* al2   = (const float*)d_in[8];
    const float* ar2   = (const float*)d_in[9];
    const float* b2    = (const float*)d_in[10];
    const float* W3    = (const float*)d_in[11];
    const float* al3   = (const float*)d_in[12];
    const float* ar3   = (const float*)d_in[13];
    const float* b3    = (const float*)d_in[14];
    const float* Wres3 = (const float*)d_in[15];
    float* out = (float*)d_out;

    const int N = NODES, E = EDGES;

    char*  ws = (char*)d_ws;
    size_t o  = 0;
    auto alloc = [&](size_t bytes) {
        size_t r = o;
        o += (bytes + 255) & ~(size_t)255;
        return r;
    };
    int*            offs   = (int*)(ws + alloc((size_t)(N + 1) * 4));
    int*            cnt    = (int*)(ws + alloc((size_t)N * 4));
    int*            csr    = (int*)(ws + alloc((size_t)E * 4));
    float*          el     = (float*)(ws + alloc((size_t)N * 6 * 4));
    float*          er     = (float*)(ws + alloc((size_t)N * 6 * 4));
    unsigned short* xb     = (unsigned short*)(ws + alloc((size_t)N * 128 * 2));
    unsigned short* featb  = (unsigned short*)(ws + alloc((size_t)N * 128 * 2)); // feat1/feat2
    unsigned short* h1b    = (unsigned short*)(ws + alloc((size_t)N * 128 * 2));
    float*          h1f    = (float*)(ws + alloc((size_t)N * 128 * 4));
    unsigned short* h2b    = (unsigned short*)(ws + alloc((size_t)N * 128 * 2));
    unsigned short* feat3b = (unsigned short*)(ws + alloc((size_t)N * 384 * 2));
    unsigned short* res3b  = (unsigned short*)(ws + alloc((size_t)N * 384 * 2));
    unsigned short* w1t    = (unsigned short*)(ws + alloc((size_t)128 * 128 * 2));
    unsigned short* w2t    = (unsigned short*)(ws + alloc((size_t)128 * 128 * 2));
    unsigned short* w3t    = (unsigned short*)(ws + alloc((size_t)768 * 128 * 2));

    const int gE = (E + 255) / 256;
    const int g4 = (N * 4 + 255) / 256;
    const int g6 = (N * 6 + 255) / 256;
    const int gA = (N + 3) / 4;
    const int gG = (N + 63) / 64;

    // ---- prep: cast x, transpose+quantize weights
    k_cast<<<(N * 128 / 4 + 255) / 256, 256, 0, stream>>>(x, xb, N * 128 / 4);
    k_prepw<<<(128 * 128 + 255) / 256, 256, 0, stream>>>(W1, w1t, 128);
    k_prepw<<<(128 * 128 + 255) / 256, 256, 0, stream>>>(W2, w2t, 128);
    k_prepw<<<(128 * 384 + 255) / 256, 256, 0, stream>>>(W3, w3t, 384);
    k_prepw<<<(128 * 384 + 255) / 256, 256, 0, stream>>>(Wres3, w3t + (size_t)384 * 128, 384);

    // ---- CSR by dst
    hipMemsetAsync(cnt, 0, (size_t)N * 4, stream);
    k_hist<<<gE, 256, 0, stream>>>(dst, cnt, E);
    k_scan<<<1, 1024, 0, stream>>>(cnt, offs, N);
    hipMemsetAsync(cnt, 0, (size_t)N * 4, stream);
    k_fill<<<gE, 256, 0, stream>>>(src, dst, offs, cnt, csr, E);

    // ---- layer 1: x -> h1 (bf16 + f32 residual copy)
    k_mgemm<128><<<gG, 256, 0, stream>>>(xb, w1t, featb, nullptr, N);
    k_elr_bf<4, 32><<<g4, 256, 0, stream>>>(featb, al1, ar1, el, er, N * 4);
    k_aggr128b<false, true><<<gA, 256, 0, stream>>>(featb, csr, offs, el, er, b1,
                                                    nullptr, h1b, h1f, N);

    // ---- layer 2: h1 -> h2 (residual = h1 f32)
    k_mgemm<128><<<gG, 256, 0, stream>>>(h1b, w2t, featb, nullptr, N);
    k_elr_bf<4, 32><<<g4, 256, 0, stream>>>(featb, al2, ar2, el, er, N * 4);
    k_aggr128b<true, false><<<gA, 256, 0, stream>>>(featb, csr, offs, el, er, b2,
                                                    h1f, h2b, nullptr, N);

    // ---- layer 3: h2 -> out (fused W3|Wres3 MFMA GEMM; head-mean)
    k_mgemm<768><<<gG, 256, 0, stream>>>(h2b, w3t, feat3b, res3b, N);
    k_elr_bf<6, 64><<<g6, 256, 0, stream>>>(feat3b, al3, ar3, el, er, N * 6);
    k_aggr384<<<gA, 256, 0, stream>>>(feat3b, csr, offs, el, er, b3, res3b, out, N);
}

// Round 6
// 478.560 us; speedup vs baseline: 2.0384x; 1.0573x over previous
//
#include <hip/hip_runtime.h>
#include <hip/hip_bf16.h>

// DistGAT: 3-layer GAT, N=50000 nodes, E=800000 edges.
// R6: aggregation restructure (R5's k_aggr384 was VALU-issue-bound: 78% VALUBusy,
//     37% HBM; all 64 lanes redundantly computed 6 heads' exp per edge).
//  - Half-wave-per-edge: lanes 0-31 take even edges, 32-63 odd edges; edge loop
//    trips halve; per-edge exp/leaky/select instruction counts halve.
//  - Wider gathers: uint2 (4 bf16 features) per lane instead of ushort/uint.
//  - Partial acc/s combined via __shfl_xor(32) (softmax normalizer is linear in
//    the edge partition); aggr384 additionally combines head-complement lanes
//    via __shfl_xor(16) and writes the 64-f32 output row from 16 lanes (float4).
// GEMM/elr/CSR kernels unchanged from R5.

#define NODES 50000
#define EDGES 800000
#define NEG 0.2f

typedef __attribute__((ext_vector_type(8))) short bh8;
typedef __attribute__((ext_vector_type(4))) float f4;

__device__ __forceinline__ float leaky(float e) { return e > 0.f ? e : NEG * e; }
__device__ __forceinline__ float blo(unsigned u) { return __uint_as_float(u << 16); }
__device__ __forceinline__ float bhi(unsigned u) { return __uint_as_float(u & 0xffff0000u); }
__device__ __forceinline__ float bf2f(unsigned short u) {
    return __uint_as_float(((unsigned)u) << 16);
}
__device__ __forceinline__ unsigned f2bf(float f) {  // RNE, low 16 bits valid
    unsigned u = __float_as_uint(f);
    return (u + 0x7fffu + ((u >> 16) & 1u)) >> 16;
}
__device__ __forceinline__ float sel4(float4 v, int h) {
    float a = (h & 1) ? v.y : v.x;
    float b = (h & 1) ? v.w : v.z;
    return (h & 2) ? b : a;
}

// swizzled byte offset in a [64][128-bf16] LDS tile (row stride 256 B)
#define SW(row, bc) (((row) << 8) + ((bc) ^ (((row) & 7) << 4)))

// ---------------------------------------------------------------- prep
__global__ void k_cast(const float* __restrict__ in, unsigned short* __restrict__ outb, int n4) {
    int gid = blockIdx.x * blockDim.x + threadIdx.x;
    if (gid >= n4) return;
    float4 v = *reinterpret_cast<const float4*>(in + (size_t)gid * 4);
    unsigned u0 = f2bf(v.x) | (f2bf(v.y) << 16);
    unsigned u1 = f2bf(v.z) | (f2bf(v.w) << 16);
    *reinterpret_cast<uint2*>(outb + (size_t)gid * 4) = make_uint2(u0, u1);
}

// W[k][f] f32 (k=128 rows, F cols) -> WT[f][128] bf16
__global__ void k_prepw(const float* __restrict__ W, unsigned short* __restrict__ WT, int F) {
    int gid = blockIdx.x * blockDim.x + threadIdx.x;
    if (gid >= 128 * F) return;
    int k = gid / F, f = gid - k * F;
    WT[(size_t)f * 128 + k] = (unsigned short)f2bf(W[gid]);
}

// ---------------------------------------------------------------- CSR build
__global__ void k_hist(const int* __restrict__ dst, int* __restrict__ cnt, int e) {
    int gid = blockIdx.x * blockDim.x + threadIdx.x;
    if (gid < e) atomicAdd(&cnt[dst[gid]], 1);
}

__global__ __launch_bounds__(1024) void k_scan(const int* __restrict__ deg,
                                               int* __restrict__ offs, int n) {
    const int CH = (n + 1023) / 1024;
    int t = threadIdx.x;
    int base = t * CH;
    int s = 0;
    for (int j = 0; j < CH; ++j) {
        int i = base + j;
        if (i < n) s += deg[i];
    }
    __shared__ int sm[1024];
    sm[t] = s;
    __syncthreads();
    for (int off = 1; off < 1024; off <<= 1) {
        int v = (t >= off) ? sm[t - off] : 0;
        __syncthreads();
        sm[t] += v;
        __syncthreads();
    }
    int run = sm[t] - s;
    for (int j = 0; j < CH; ++j) {
        int i = base + j;
        if (i < n) { offs[i] = run; run += deg[i]; }
    }
    if (t == 1023) offs[n] = sm[1023];
}

__global__ void k_fill(const int* __restrict__ src, const int* __restrict__ dst,
                       const int* __restrict__ offs, int* __restrict__ cur,
                       int* __restrict__ csr, int e) {
    int gid = blockIdx.x * blockDim.x + threadIdx.x;
    if (gid < e) {
        int d = dst[gid];
        int pos = offs[d] + atomicAdd(&cur[d], 1);
        csr[pos] = src[gid];
    }
}

// ---------------------------------------------------------------- MFMA GEMM
// C[M,F] = A[M,128] @ B[128,F], A bf16 row-major, BT bf16 [F][128].
// 64x64 tile per ct; 4 waves, each 32x32 (2x2 frags of 16x16x32).
template <int F>
__global__ __launch_bounds__(256) void k_mgemm(const unsigned short* __restrict__ A,
                                               const unsigned short* __restrict__ BT,
                                               unsigned short* __restrict__ C0,
                                               unsigned short* __restrict__ C1,
                                               int nrows) {
    __shared__ char Alds[64 * 256];
    __shared__ char Blds[64 * 256];
    const int t  = threadIdx.x;
    const int n0 = blockIdx.x * 64;
    const int w  = t >> 6;
    const int l  = t & 63;
    const int lr = l & 15;
    const int lk = l >> 4;

    // stage A once: 64 rows x 128 bf16
    {
        int col8 = (t & 15) * 8;
        int bc   = col8 * 2;
#pragma unroll
        for (int p = 0; p < 4; ++p) {
            int row = p * 16 + (t >> 4);
            int gr  = n0 + row;
            uint4 v = make_uint4(0, 0, 0, 0);
            if (gr < nrows) v = *reinterpret_cast<const uint4*>(A + (size_t)gr * 128 + col8);
            *reinterpret_cast<uint4*>(Alds + SW(row, bc)) = v;
        }
    }

    const int rbase = (w & 1) * 32;
    const int cbase = (w >> 1) * 32;

    for (int ct = 0; ct < F / 64; ++ct) {
        __syncthreads();
        {   // stage BT rows [ct*64, ct*64+64)
            int col8 = (t & 15) * 8;
            int bc   = col8 * 2;
#pragma unroll
            for (int p = 0; p < 4; ++p) {
                int row = p * 16 + (t >> 4);
                uint4 v = *reinterpret_cast<const uint4*>(BT + (size_t)(ct * 64 + row) * 128 + col8);
                *reinterpret_cast<uint4*>(Blds + SW(row, bc)) = v;
            }
        }
        __syncthreads();

        f4 acc00 = {0.f, 0.f, 0.f, 0.f}, acc01 = {0.f, 0.f, 0.f, 0.f};
        f4 acc10 = {0.f, 0.f, 0.f, 0.f}, acc11 = {0.f, 0.f, 0.f, 0.f};
#pragma unroll
        for (int kk = 0; kk < 4; ++kk) {
            int bck = kk * 64 + lk * 16;
            bh8 a0 = *reinterpret_cast<const bh8*>(Alds + SW(rbase + lr, bck));
            bh8 a1 = *reinterpret_cast<const bh8*>(Alds + SW(rbase + 16 + lr, bck));
            bh8 b0 = *reinterpret_cast<const bh8*>(Blds + SW(cbase + lr, bck));
            bh8 b1 = *reinterpret_cast<const bh8*>(Blds + SW(cbase + 16 + lr, bck));
            acc00 = __builtin_amdgcn_mfma_f32_16x16x32_bf16(a0, b0, acc00, 0, 0, 0);
            acc01 = __builtin_amdgcn_mfma_f32_16x16x32_bf16(a0, b1, acc01, 0, 0, 0);
            acc10 = __builtin_amdgcn_mfma_f32_16x16x32_bf16(a1, b0, acc10, 0, 0, 0);
            acc11 = __builtin_amdgcn_mfma_f32_16x16x32_bf16(a1, b1, acc11, 0, 0, 0);
        }

        // epilogue: C row = (lane>>4)*4 + reg, col = cbase + n*16 + (lane&15)
        unsigned short* dst = (F == 128) ? C0 : (ct < 6 ? C0 : C1);
        const int width  = (F == 128) ? 128 : 384;
        const int cb     = (F == 128) ? ct * 64 : (ct < 6 ? ct * 64 : ct * 64 - 384);
        const f4* accs[4] = {&acc00, &acc01, &acc10, &acc11};
#pragma unroll
        for (int m = 0; m < 2; ++m) {
#pragma unroll
            for (int j = 0; j < 4; ++j) {
                int gr = n0 + rbase + m * 16 + lk * 4 + j;
                if (gr >= nrows) continue;
#pragma unroll
                for (int n = 0; n < 2; ++n) {
                    float v = (*accs[m * 2 + n])[j];
                    dst[(size_t)gr * width + cb + cbase + n * 16 + lr] = (unsigned short)f2bf(v);
                }
            }
        }
    }
}

// ---------------------------------------------------------------- el / er from bf16 feat
template <int H, int D>
__global__ void k_elr_bf(const unsigned short* __restrict__ feat,
                         const float* __restrict__ al, const float* __restrict__ ar,
                         float* __restrict__ el, float* __restrict__ er, int total) {
    int gid = blockIdx.x * blockDim.x + threadIdx.x;
    if (gid >= total) return;
    int n = gid / H, h = gid - n * H;
    const uint4* f = reinterpret_cast<const uint4*>(feat + (size_t)n * (H * D) + h * D);
    const float4* a = reinterpret_cast<const float4*>(al + h * D);
    const float4* r = reinterpret_cast<const float4*>(ar + h * D);
    float sl = 0.f, sr = 0.f;
#pragma unroll
    for (int j = 0; j < D / 8; ++j) {
        uint4 v = f[j];
        float4 a0 = a[2 * j], a1 = a[2 * j + 1];
        float4 r0 = r[2 * j], r1 = r[2 * j + 1];
        float x0 = blo(v.x), x1 = bhi(v.x), x2 = blo(v.y), x3 = bhi(v.y);
        float x4 = blo(v.z), x5 = bhi(v.z), x6 = blo(v.w), x7 = bhi(v.w);
        sl += x0 * a0.x + x1 * a0.y + x2 * a0.z + x3 * a0.w +
              x4 * a1.x + x5 * a1.y + x6 * a1.z + x7 * a1.w;
        sr += x0 * r0.x + x1 * r0.y + x2 * r0.z + x3 * r0.w +
              x4 * r1.x + x5 * r1.y + x6 * r1.z + x7 * r1.w;
    }
    el[gid] = sl;
    er[gid] = sr;
}

// ---------------------------------------------------------------- aggregation, F=128, bf16
// Half-wave per edge: lanes 0-31 even edges, 32-63 odd edges; lane owns 4
// consecutive features f=4*ll (head ll>>3) via one uint2 gather. Partial acc/s
// combined with shfl_xor(32). res/out may alias semantics preserved: res read
// happens after combine, writes only from lanes <32.
template <bool HASRES, bool WRITEF32>
__global__ __launch_bounds__(256) void k_aggr128b(
    const unsigned short* __restrict__ feat, const int* __restrict__ csr,
    const int* __restrict__ offs, const float* __restrict__ el,
    const float* __restrict__ er, const float* __restrict__ bias,
    const float* __restrict__ resf, unsigned short* __restrict__ outb,
    float* __restrict__ outf, int nnodes) {
    int node = blockIdx.x * 4 + (threadIdx.x >> 6);
    if (node >= nnodes) return;
    int l = threadIdx.x & 63;
    int half = l >> 5;
    int ll = l & 31;
    int h = ll >> 3;                 // head 0..3 (features 4*ll .. 4*ll+3)
    float4 ern = *reinterpret_cast<const float4*>(er + (size_t)node * 4);
    float erh = sel4(ern, h);
    int o0 = offs[node], o1 = offs[node + 1];
    float acc0 = 0.f, acc1 = 0.f, acc2 = 0.f, acc3 = 0.f, s = 0.f;
    int nt = (o1 - o0 + 1) >> 1;
#pragma unroll 2
    for (int t = 0; t < nt; ++t) {
        int ei = o0 + 2 * t + half;
        bool v = ei < o1;
        int sidx = csr[v ? ei : o0];
        float4 la = *reinterpret_cast<const float4*>(el + (size_t)sidx * 4);
        float e = leaky(sel4(la, h) + erh);
        float w = v ? __expf(e) : 0.f;
        s += w;
        uint2 u = *reinterpret_cast<const uint2*>(feat + (size_t)sidx * 128 + 4 * ll);
        acc0 = fmaf(w, blo(u.x), acc0);
        acc1 = fmaf(w, bhi(u.x), acc1);
        acc2 = fmaf(w, blo(u.y), acc2);
        acc3 = fmaf(w, bhi(u.y), acc3);
    }
    s    += __shfl_xor(s, 32);
    acc0 += __shfl_xor(acc0, 32);
    acc1 += __shfl_xor(acc1, 32);
    acc2 += __shfl_xor(acc2, 32);
    acc3 += __shfl_xor(acc3, 32);
    float inv = (o1 > o0) ? 1.f / s : 0.f;
    int f = 4 * ll;
    float4 bi = *reinterpret_cast<const float4*>(bias + f);
    float r0 = acc0 * inv + bi.x;
    float r1 = acc1 * inv + bi.y;
    float r2 = acc2 * inv + bi.z;
    float r3 = acc3 * inv + bi.w;
    if (HASRES) {
        float4 rv = *reinterpret_cast<const float4*>(resf + (size_t)node * 128 + f);
        r0 += rv.x; r1 += rv.y; r2 += rv.z; r3 += rv.w;
    }
    r0 = (r0 > 0.f) ? r0 : (__expf(r0) - 1.f);
    r1 = (r1 > 0.f) ? r1 : (__expf(r1) - 1.f);
    r2 = (r2 > 0.f) ? r2 : (__expf(r2) - 1.f);
    r3 = (r3 > 0.f) ? r3 : (__expf(r3) - 1.f);
    if (half == 0) {
        unsigned u0 = f2bf(r0) | (f2bf(r1) << 16);
        unsigned u1 = f2bf(r2) | (f2bf(r3) << 16);
        *reinterpret_cast<uint2*>(outb + (size_t)node * 128 + f) = make_uint2(u0, u1);
        if (WRITEF32)
            *reinterpret_cast<float4*>(outf + (size_t)node * 128 + f) =
                make_float4(r0, r1, r2, r3);
    }
}

// ---------------------------------------------------------------- aggregation, F=384 (bf16)
// Half-wave per edge; lane owns features f_j = j*128 + 4*ll (head 2j+(ll>>4))
// via 3 uint2 gathers; 3 exp per lane per edge (was 6 on all 64 lanes).
// Combine: edge parity via shfl_xor(32); head complement via shfl_xor(16);
// 16 lanes write the 64-f32 output row (float4).
__global__ __launch_bounds__(256) void k_aggr384(
    const unsigned short* __restrict__ feat, const int* __restrict__ csr,
    const int* __restrict__ offs, const float* __restrict__ el,
    const float* __restrict__ er, const float* __restrict__ b3,
    const unsigned short* __restrict__ res3, float* __restrict__ out, int nnodes) {
    int node = blockIdx.x * 4 + (threadIdx.x >> 6);
    if (node >= nnodes) return;
    int l = threadIdx.x & 63;
    int half = l >> 5;
    int ll = l & 31;
    int hi = ll >> 4;                 // head selector within pair
    float erh[3];
#pragma unroll
    for (int j = 0; j < 3; ++j) {
        float2 e2 = *reinterpret_cast<const float2*>(er + (size_t)node * 6 + 2 * j);
        erh[j] = hi ? e2.y : e2.x;
    }
    int o0 = offs[node], o1 = offs[node + 1];
    float a00 = 0.f, a01 = 0.f, a02 = 0.f, a03 = 0.f;
    float a10 = 0.f, a11 = 0.f, a12 = 0.f, a13 = 0.f;
    float a20 = 0.f, a21 = 0.f, a22 = 0.f, a23 = 0.f;
    float s0 = 0.f, s1 = 0.f, s2 = 0.f;
    int nt = (o1 - o0 + 1) >> 1;
#pragma unroll 2
    for (int t = 0; t < nt; ++t) {
        int ei = o0 + 2 * t + half;
        bool v = ei < o1;
        int sidx = csr[v ? ei : o0];
        const unsigned short* fr = feat + (size_t)sidx * 384 + 4 * ll;
        const float* le = el + (size_t)sidx * 6;
        float2 e0 = *reinterpret_cast<const float2*>(le + 0);
        float2 e1 = *reinterpret_cast<const float2*>(le + 2);
        float2 e2 = *reinterpret_cast<const float2*>(le + 4);
        float w0 = v ? __expf(leaky((hi ? e0.y : e0.x) + erh[0])) : 0.f;
        float w1 = v ? __expf(leaky((hi ? e1.y : e1.x) + erh[1])) : 0.f;
        float w2 = v ? __expf(leaky((hi ? e2.y : e2.x) + erh[2])) : 0.f;
        s0 += w0; s1 += w1; s2 += w2;
        uint2 u0 = *reinterpret_cast<const uint2*>(fr);
        uint2 u1 = *reinterpret_cast<const uint2*>(fr + 128);
        uint2 u2 = *reinterpret_cast<const uint2*>(fr + 256);
        a00 = fmaf(w0, blo(u0.x), a00); a01 = fmaf(w0, bhi(u0.x), a01);
        a02 = fmaf(w0, blo(u0.y), a02); a03 = fmaf(w0, bhi(u0.y), a03);
        a10 = fmaf(w1, blo(u1.x), a10); a11 = fmaf(w1, bhi(u1.x), a11);
        a12 = fmaf(w1, blo(u1.y), a12); a13 = fmaf(w1, bhi(u1.y), a13);
        a20 = fmaf(w2, blo(u2.x), a20); a21 = fmaf(w2, bhi(u2.x), a21);
        a22 = fmaf(w2, blo(u2.y), a22); a23 = fmaf(w2, bhi(u2.y), a23);
    }
    bool has = o1 > o0;
    float part0 = 0.f, part1 = 0.f, part2 = 0.f, part3 = 0.f;
    // j = 0
    {
        s0 += __shfl_xor(s0, 32);
        float inv = has ? 1.f / s0 : 0.f;
        part0 += (a00 + __shfl_xor(a00, 32)) * inv;
        part1 += (a01 + __shfl_xor(a01, 32)) * inv;
        part2 += (a02 + __shfl_xor(a02, 32)) * inv;
        part3 += (a03 + __shfl_xor(a03, 32)) * inv;
        int f = 4 * ll;
        uint2 r = *reinterpret_cast<const uint2*>(res3 + (size_t)node * 384 + f);
        float4 bb = *reinterpret_cast<const float4*>(b3 + f);
        part0 += blo(r.x) + bb.x; part1 += bhi(r.x) + bb.y;
        part2 += blo(r.y) + bb.z; part3 += bhi(r.y) + bb.w;
    }
    // j = 1
    {
        s1 += __shfl_xor(s1, 32);
        float inv = has ? 1.f / s1 : 0.f;
        part0 += (a10 + __shfl_xor(a10, 32)) * inv;
        part1 += (a11 + __shfl_xor(a11, 32)) * inv;
        part2 += (a12 + __shfl_xor(a12, 32)) * inv;
        part3 += (a13 + __shfl_xor(a13, 32)) * inv;
        int f = 128 + 4 * ll;
        uint2 r = *reinterpret_cast<const uint2*>(res3 + (size_t)node * 384 + f);
        float4 bb = *reinterpret_cast<const float4*>(b3 + f);
        part0 += blo(r.x) + bb.x; part1 += bhi(r.x) + bb.y;
        part2 += blo(r.y) + bb.z; part3 += bhi(r.y) + bb.w;
    }
    // j = 2
    {
        s2 += __shfl_xor(s2, 32);
        float inv = has ? 1.f / s2 : 0.f;
        part0 += (a20 + __shfl_xor(a20, 32)) * inv;
        part1 += (a21 + __shfl_xor(a21, 32)) * inv;
        part2 += (a22 + __shfl_xor(a22, 32)) * inv;
        part3 += (a23 + __shfl_xor(a23, 32)) * inv;
        int f = 256 + 4 * ll;
        uint2 r = *reinterpret_cast<const uint2*>(res3 + (size_t)node * 384 + f);
        float4 bb = *reinterpret_cast<const float4*>(b3 + f);
        part0 += blo(r.x) + bb.x; part1 += bhi(r.x) + bb.y;
        part2 += blo(r.y) + bb.z; part3 += bhi(r.y) + bb.w;
    }
    // combine head-complement lanes (ll and ll+16 hold heads {0,2,4} vs {1,3,5})
    part0 += __shfl_xor(part0, 16);
    part1 += __shfl_xor(part1, 16);
    part2 += __shfl_xor(part2, 16);
    part3 += __shfl_xor(part3, 16);
    if (l < 16) {
        *reinterpret_cast<float4*>(out + (size_t)node * 64 + 4 * l) =
            make_float4(part0 * (1.f / 6.f), part1 * (1.f / 6.f),
                        part2 * (1.f / 6.f), part3 * (1.f / 6.f));
    }
}

// ---------------------------------------------------------------- launch
extern "C" void kernel_launch(void* const* d_in, const int* in_sizes, int n_in,
                              void* d_out, int out_size, void* d_ws, size_t ws_size,
                              hipStream_t stream) {
    const float* x     = (const float*)d_in[0];
    const int*   src   = (const int*)d_in[1];
    const int*   dst   = (const int*)d_in[2];
    const float* W1    = (const float*)d_in[3];
    const float* al1   = (const float*)d_in[4];
    const float* ar1   = (const float*)d_in[5];
    const float* b1    = (const float*)d_in[6];
    const float* W2    = (const float*)d_in[7];
    const float* al2   = (const float*)d_in[8];
    const float* ar2   = (const float*)d_in[9];
    const float* b2    = (const float*)d_in[10];
    const float* W3    = (const float*)d_in[11];
    const float* al3   = (const float*)d_in[12];
    const float* ar3   = (const float*)d_in[13];
    const float* b3    = (const float*)d_in[14];
    const float* Wres3 = (const float*)d_in[15];
    float* out = (float*)d_out;

    const int N = NODES, E = EDGES;

    char*  ws = (char*)d_ws;
    size_t o  = 0;
    auto alloc = [&](size_t bytes) {
        size_t r = o;
        o += (bytes + 255) & ~(size_t)255;
        return r;
    };
    int*            offs   = (int*)(ws + alloc((size_t)(N + 1) * 4));
    int*            cnt    = (int*)(ws + alloc((size_t)N * 4));
    int*            csr    = (int*)(ws + alloc((size_t)E * 4));
    float*          el     = (float*)(ws + alloc((size_t)N * 6 * 4));
    float*          er     = (float*)(ws + alloc((size_t)N * 6 * 4));
    unsigned short* xb     = (unsigned short*)(ws + alloc((size_t)N * 128 * 2));
    unsigned short* featb  = (unsigned short*)(ws + alloc((size_t)N * 128 * 2)); // feat1/feat2
    unsigned short* h1b    = (unsigned short*)(ws + alloc((size_t)N * 128 * 2));
    float*          h1f    = (float*)(ws + alloc((size_t)N * 128 * 4));
    unsigned short* h2b    = (unsigned short*)(ws + alloc((size_t)N * 128 * 2));
    unsigned short* feat3b = (unsigned short*)(ws + alloc((size_t)N * 384 * 2));
    unsigned short* res3b  = (unsigned short*)(ws + alloc((size_t)N * 384 * 2));
    unsigned short* w1t    = (unsigned short*)(ws + alloc((size_t)128 * 128 * 2));
    unsigned short* w2t    = (unsigned short*)(ws + alloc((size_t)128 * 128 * 2));
    unsigned short* w3t    = (unsigned short*)(ws + alloc((size_t)768 * 128 * 2));

    const int gE = (E + 255) / 256;
    const int g4 = (N * 4 + 255) / 256;
    const int g6 = (N * 6 + 255) / 256;
    const int gA = (N + 3) / 4;
    const int gG = (N + 63) / 64;

    // ---- prep: cast x, transpose+quantize weights
    k_cast<<<(N * 128 / 4 + 255) / 256, 256, 0, stream>>>(x, xb, N * 128 / 4);
    k_prepw<<<(128 * 128 + 255) / 256, 256, 0, stream>>>(W1, w1t, 128);
    k_prepw<<<(128 * 128 + 255) / 256, 256, 0, stream>>>(W2, w2t, 128);
    k_prepw<<<(128 * 384 + 255) / 256, 256, 0, stream>>>(W3, w3t, 384);
    k_prepw<<<(128 * 384 + 255) / 256, 256, 0, stream>>>(Wres3, w3t + (size_t)384 * 128, 384);

    // ---- CSR by dst
    hipMemsetAsync(cnt, 0, (size_t)N * 4, stream);
    k_hist<<<gE, 256, 0, stream>>>(dst, cnt, E);
    k_scan<<<1, 1024, 0, stream>>>(cnt, offs, N);
    hipMemsetAsync(cnt, 0, (size_t)N * 4, stream);
    k_fill<<<gE, 256, 0, stream>>>(src, dst, offs, cnt, csr, E);

    // ---- layer 1: x -> h1 (bf16 + f32 residual copy)
    k_mgemm<128><<<gG, 256, 0, stream>>>(xb, w1t, featb, nullptr, N);
    k_elr_bf<4, 32><<<g4, 256, 0, stream>>>(featb, al1, ar1, el, er, N * 4);
    k_aggr128b<false, true><<<gA, 256, 0, stream>>>(featb, csr, offs, el, er, b1,
                                                    nullptr, h1b, h1f, N);

    // ---- layer 2: h1 -> h2 (residual = h1 f32)
    k_mgemm<128><<<gG, 256, 0, stream>>>(h1b, w2t, featb, nullptr, N);
    k_elr_bf<4, 32><<<g4, 256, 0, stream>>>(featb, al2, ar2, el, er, N * 4);
    k_aggr128b<true, false><<<gA, 256, 0, stream>>>(featb, csr, offs, el, er, b2,
                                                    h1f, h2b, nullptr, N);

    // ---- layer 3: h2 -> out (fused W3|Wres3 MFMA GEMM; head-mean)
    k_mgemm<768><<<gG, 256, 0, stream>>>(h2b, w3t, feat3b, res3b, N);
    k_elr_bf<6, 64><<<g6, 256, 0, stream>>>(feat3b, al3, ar3, el, er, N * 6);
    k_aggr384<<<gA, 256, 0, stream>>>(feat3b, csr, offs, el, er, b3, res3b, out, N);
}